// Round 9
// baseline (185.867 us; speedup 1.0000x reference)
//
#include <hip/hip_runtime.h>
#include <math.h>

#define BB_ 8
#define CC_ 256
#define LL_ 2048
#define HEADS_ 4
#define DHEAD_ 32
#define HID_ 128
#define EPS_ 1e-5f
#define SCALE_ 0.17677669529663687f   // 32^-0.5
#define K1_ (SCALE_ * 1.44269504088896f)   // folded into q at bf16-write time

typedef short v8s  __attribute__((ext_vector_type(8)));
typedef float v4f  __attribute__((ext_vector_type(4)));
typedef float v16f __attribute__((ext_vector_type(16)));
typedef unsigned v4u __attribute__((ext_vector_type(4)));

__device__ inline short f2bf(float x) {   // RNE f32 -> bf16 bits
    union { float f; unsigned u; } a; a.f = x;
    unsigned r = a.u + 0x7fffu + ((a.u >> 16) & 1u);
    return (short)(r >> 16);
}
__device__ inline unsigned fbits(float x) { union { float f; unsigned u; } a; a.f = x; return a.u; }

// ---------------------------------------------------------------------------
// Kernel 0: weight prep — fp32 -> bf16. wqkv[384][256] (q|k|v), wo[256][128].
// ---------------------------------------------------------------------------
__global__ __launch_bounds__(256) void k_prep(
    const float* __restrict__ Wq, const float* __restrict__ Wk, const float* __restrict__ Wv,
    const float* __restrict__ Wo, short* __restrict__ wqkv, short* __restrict__ wo)
{
    int idx = blockIdx.x * 256 + threadIdx.x;
    if (idx < 384 * 256) {
        int o = idx >> 8, c = idx & 255;
        float s;
        if (o < 128)      s = Wq[o * 256 + c];
        else if (o < 256) s = Wk[(o - 128) * 256 + c];
        else              s = Wv[(o - 256) * 256 + c];
        wqkv[idx] = f2bf(s);
    } else {
        int i2 = idx - 384 * 256;
        wo[i2] = f2bf(Wo[i2]);
    }
}

// ---------------------------------------------------------------------------
// Kernel 1: channel-LayerNorm + QKV projection via MFMA (unchanged r8).
// q pre-scaled by SCALE*log2(e). q,k: [B*H, L, 32]; v: [B*H, 32, L] bf16.
// ---------------------------------------------------------------------------
__global__ __launch_bounds__(512) void k_ln_qkv(
    const float* __restrict__ x, const float* __restrict__ g, const float* __restrict__ bvec,
    const short* __restrict__ wqkv,
    short* __restrict__ q, short* __restrict__ k, short* __restrict__ v)
{
    __shared__ float xn[CC_ * 33];
    __shared__ short xnT[32 * 264];      // normalized bf16, later reused as q|k staging
    __shared__ short st2[128 * 48];      // v staging: [o'][l], stride 48
    __shared__ float ps_[16 * 32], ps2_[16 * 32];
    __shared__ float cmean[32], crstd[32];
    const int b   = blockIdx.y;
    const int l0  = blockIdx.x * 32;
    const int tid = threadIdx.x;

    for (int idx = tid; idx < CC_ * 32; idx += 512) {
        int c = idx >> 5, ls = idx & 31;
        xn[c * 33 + ls] = x[((size_t)b * CC_ + c) * LL_ + l0 + ls];
    }
    __syncthreads();

    {
        int part = tid >> 5, col = tid & 31;   // 16 partials x 32 cols
        float s = 0.f, s2 = 0.f;
        #pragma unroll
        for (int cc = 0; cc < 16; ++cc) {
            float t = xn[(part * 16 + cc) * 33 + col];
            s += t; s2 += t * t;
        }
        ps_[part * 32 + col] = s; ps2_[part * 32 + col] = s2;
    }
    __syncthreads();
    if (tid < 32) {
        float s = 0.f, s2 = 0.f;
        #pragma unroll
        for (int p = 0; p < 16; ++p) { s += ps_[p * 32 + tid]; s2 += ps2_[p * 32 + tid]; }
        float mean = s * (1.f / CC_);
        float var  = s2 * (1.f / CC_) - mean * mean;
        cmean[tid] = mean;
        crstd[tid] = rsqrtf(var + EPS_);
    }
    __syncthreads();

    for (int idx = tid; idx < 32 * 128; idx += 512) {
        int ls = idx >> 7, cc = idx & 127;
        int c0 = 2 * cc, c1 = 2 * cc + 1;
        float mu = cmean[ls], rs = crstd[ls];
        float a0 = (xn[c0 * 33 + ls] - mu) * rs * g[c0] + bvec[c0];
        float a1 = (xn[c1 * 33 + ls] - mu) * rs * g[c1] + bvec[c1];
        xnT[ls * 264 + c0]     = f2bf(a0);
        xnT[ls * 264 + c0 + 1] = f2bf(a1);
    }
    __syncthreads();

    const int wave = tid >> 6, lane = tid & 63;
    const int n = lane & 15, quad = lane >> 4;
    const int rowbase = (wave >> 2) * 16;       // 2 row-groups
    const int colbase = (wave & 3) * 96;        // 4 col-groups of 96

    v4f acc[6];
    #pragma unroll
    for (int ct = 0; ct < 6; ++ct) acc[ct] = (v4f){0.f, 0.f, 0.f, 0.f};

    #pragma unroll
    for (int ks = 0; ks < 8; ++ks) {
        const v8s af = *(const v8s*)(xnT + (rowbase + n) * 264 + ks * 32 + quad * 8);
        #pragma unroll
        for (int ct = 0; ct < 6; ++ct) {
            const v8s bfrag = *(const v8s*)(wqkv + (size_t)(colbase + ct * 16 + n) * 256 + ks * 32 + quad * 8);
            acc[ct] = __builtin_amdgcn_mfma_f32_16x16x32_bf16(af, bfrag, acc[ct], 0, 0, 0);
        }
    }
    __syncthreads();   // all waves done reading xnT; safe to reuse as staging

    #pragma unroll
    for (int ct = 0; ct < 6; ++ct) {
        int o = colbase + ct * 16 + n;
        #pragma unroll
        for (int r = 0; r < 4; ++r) {
            int l = rowbase + quad * 4 + r;
            float val = acc[ct][r];
            if (o < 128)      xnT[l * 264 + o] = f2bf(val * K1_);
            else if (o < 256) xnT[l * 264 + o] = f2bf(val);
            else              st2[(o - 256) * 48 + l] = f2bf(val);
        }
    }
    __syncthreads();

    {
        int u = tid;
        int h = u >> 7, rest = u & 127;
        int l = rest >> 2, dg = rest & 3;
        size_t bh = (size_t)b * HEADS_ + h;
        v8s qv = *(const v8s*)(xnT + l * 264 + h * 32 + dg * 8);
        *(v8s*)(q + (bh * LL_ + l0 + l) * DHEAD_ + dg * 8) = qv;
        v8s kv = *(const v8s*)(xnT + l * 264 + 128 + h * 32 + dg * 8);
        *(v8s*)(k + (bh * LL_ + l0 + l) * DHEAD_ + dg * 8) = kv;

        int op = u >> 2, lg = u & 3;
        v8s vv = *(const v8s*)(st2 + op * 48 + lg * 8);
        int h2 = op >> 5, d = op & 31;
        *(v8s*)(v + (((size_t)b * HEADS_ + h2) * DHEAD_ + d) * LL_ + l0 + lg * 8) = vv;
    }
}

// ---------------------------------------------------------------------------
// Kernel 2: flash attention, 32x32x16 MFMA, S^T, no max-subtraction.
// 512 threads = 2 q-waves x 4 key-quarters (partials exactly additive).
// Grid 1024 blocks -> 4 blocks/CU -> 32 waves/CU (100%): latency hiding by
// TLP instead of prefetch depth. P relayout C->A in-register via
// permlane32_swap. End: kh>0 waves dump O/psum to LDS, kh==0 combines.
// ---------------------------------------------------------------------------
__global__ __launch_bounds__(512) void k_attn(
    const short* __restrict__ q, const short* __restrict__ k, const short* __restrict__ v,
    short* __restrict__ ao)
{
    __shared__ float Ost[2][3][32][32];     // [q-wave][kh-1][q-row][d]
    __shared__ float psumst[2][3][32];
    const int bh   = blockIdx.y;
    const int b    = bh >> 2, h = bh & 3;
    const int tid  = threadIdx.x;
    const int wave = tid >> 6, lane = tid & 63;
    const int wq   = wave & 1;           // q-subtile (2 per block)
    const int kh   = wave >> 1;          // key quarter: [kh*512, kh*512+512)
    const int m    = lane & 31;
    const int half = lane >> 5;
    const size_t kvbase = (size_t)bh * LL_ * DHEAD_;   // q,k: [bh][l][32]
    const size_t vbase  = (size_t)bh * DHEAD_ * LL_;   // v:   [bh][d][L]

    const int q0 = blockIdx.x * 64 + wq * 32;
    const int kb = kh * 512;

    // persistent Q B-frags: B[k=d][n=q], d = half*8+j (+16)
    const v8s qf0 = *(const v8s*)(q + kvbase + (size_t)(q0 + m) * DHEAD_ + half * 8);
    const v8s qf1 = *(const v8s*)(q + kvbase + (size_t)(q0 + m) * DHEAD_ + 16 + half * 8);

    v16f O = {};
    float psum = 0.f;

    v8s kf0 = *(const v8s*)(k + kvbase + (size_t)(kb + m) * DHEAD_ + half * 8);
    v8s kf1 = *(const v8s*)(k + kvbase + (size_t)(kb + m) * DHEAD_ + 16 + half * 8);
    v8s vf0 = *(const v8s*)(v + vbase + (size_t)m * LL_ + kb + half * 8);
    v8s vf1 = *(const v8s*)(v + vbase + (size_t)m * LL_ + kb + 16 + half * 8);

    for (int kt = 0; kt < 512; kt += 32) {
        // scores: S^T[key][q] = sum_d K[key][d] * Q[q][d]  (q pre-scaled by K1)
        v16f S = __builtin_amdgcn_mfma_f32_32x32x16_bf16(kf0, qf0, (v16f){}, 0, 0, 0);
        S      = __builtin_amdgcn_mfma_f32_32x32x16_bf16(kf1, qf1, S,        0, 0, 0);

        const int ktn = kb + ((kt + 32) & 511);   // wrap within own quarter
        kf0 = *(const v8s*)(k + kvbase + (size_t)(ktn + m) * DHEAD_ + half * 8);
        kf1 = *(const v8s*)(k + kvbase + (size_t)(ktn + m) * DHEAD_ + 16 + half * 8);
        v8s vf0n = *(const v8s*)(v + vbase + (size_t)m * LL_ + ktn + half * 8);
        v8s vf1n = *(const v8s*)(v + vbase + (size_t)m * LL_ + ktn + 16 + half * 8);

        // p = exp2(S); pack key-pairs into dwords e0..e7 (bf16 half-up)
        unsigned e[8];
        #pragma unroll
        for (int i = 0; i < 8; ++i) {
            float pa = __builtin_amdgcn_exp2f(S[2 * i]);
            float pb = __builtin_amdgcn_exp2f(S[2 * i + 1]);
            psum += pa + pb;
            e[i] = __builtin_amdgcn_perm(fbits(pb) + 0x8000u, fbits(pa) + 0x8000u, 0x07060302u);
        }
        // C->A relayout: swap high-half(e_lo) with low-half(e_hi)
        v4u f1, f2;
#if __has_builtin(__builtin_amdgcn_permlane32_swap)
        {
            auto r02 = __builtin_amdgcn_permlane32_swap(e[0], e[2], false, false);
            auto r13 = __builtin_amdgcn_permlane32_swap(e[1], e[3], false, false);
            auto r46 = __builtin_amdgcn_permlane32_swap(e[4], e[6], false, false);
            auto r57 = __builtin_amdgcn_permlane32_swap(e[5], e[7], false, false);
            f1 = (v4u){r02[0], r13[0], r02[1], r13[1]};
            f2 = (v4u){r46[0], r57[0], r46[1], r57[1]};
        }
#else
        {
            unsigned o0 = __shfl_xor(e[0], 32, 64), o1 = __shfl_xor(e[1], 32, 64);
            unsigned o2 = __shfl_xor(e[2], 32, 64), o3 = __shfl_xor(e[3], 32, 64);
            unsigned o4 = __shfl_xor(e[4], 32, 64), o5 = __shfl_xor(e[5], 32, 64);
            unsigned o6 = __shfl_xor(e[6], 32, 64), o7 = __shfl_xor(e[7], 32, 64);
            f1 = half ? (v4u){o2, o3, e[2], e[3]} : (v4u){e[0], e[1], o0, o1};
            f2 = half ? (v4u){o6, o7, e[6], e[7]} : (v4u){e[4], e[5], o4, o5};
        }
#endif
        // PV: O[q][d] += P[q][key] * V[key][d]
        O = __builtin_amdgcn_mfma_f32_32x32x16_bf16(__builtin_bit_cast(v8s, f1), vf0, O, 0, 0, 0);
        O = __builtin_amdgcn_mfma_f32_32x32x16_bf16(__builtin_bit_cast(v8s, f2), vf1, O, 0, 0, 0);

        vf0 = vf0n; vf1 = vf1n;
    }

    // in-wave: combine lane-halves -> lane m holds den-partial for q = m
    psum += __shfl_xor(psum, 32, 64);

    // cross-wave combine of the four key-quarters through LDS
    if (kh > 0) {
        #pragma unroll
        for (int r = 0; r < 16; ++r) {
            int qr = (r & 3) + 8 * (r >> 2) + 4 * half;
            Ost[wq][kh - 1][qr][m] = O[r];
        }
        if (half == 0) psumst[wq][kh - 1][m] = psum;
    }
    __syncthreads();
    if (kh == 0) {
        float den = psum + psumst[wq][0][m] + psumst[wq][1][m] + psumst[wq][2][m];
        float invden = 1.f / den;                    // lane m: 1/den(q=m)
        #pragma unroll
        for (int r = 0; r < 16; ++r) {
            int qr = (r & 3) + 8 * (r >> 2) + 4 * half;
            float inv = __shfl(invden, qr, 64);
            float val = (O[r] + Ost[wq][0][qr][m] + Ost[wq][1][qr][m] + Ost[wq][2][qr][m]) * inv;
            int row = q0 + qr;
            ao[((size_t)b * LL_ + row) * HID_ + h * DHEAD_ + m] = f2bf(val);
        }
    }
}

// ---------------------------------------------------------------------------
// Kernel 3: output projection via MFMA + bias + residual. 16-l x 128-o
// blocks (grid.y = o-half): 2048 blocks -> 8 blocks/CU -> 32 waves/CU.
// ---------------------------------------------------------------------------
__global__ __launch_bounds__(256) void k_oproj(
    const short* __restrict__ ao, const short* __restrict__ wo, const float* __restrict__ bo,
    const float* __restrict__ x, float* __restrict__ out)
{
    const int b = blockIdx.z;
    const int l0 = blockIdx.x * 16;
    const int obase = blockIdx.y * 8;            // in 16-o tiles
    const int tid = threadIdx.x;
    const int wave = tid >> 6, lane = tid & 63;
    const int n = lane & 15, quad = lane >> 4;

    v8s bf[4];
    #pragma unroll
    for (int ks = 0; ks < 4; ++ks)
        bf[ks] = *(const v8s*)(ao + ((size_t)b * LL_ + l0 + n) * HID_ + ks * 32 + quad * 8);

    #pragma unroll
    for (int oi_ = 0; oi_ < 2; ++oi_) {
        int ot = obase + wave * 2 + oi_;
        v4f acc = {0.f, 0.f, 0.f, 0.f};
        #pragma unroll
        for (int ks = 0; ks < 4; ++ks) {
            const v8s af = *(const v8s*)(wo + (size_t)(ot * 16 + n) * HID_ + ks * 32 + quad * 8);
            acc = __builtin_amdgcn_mfma_f32_16x16x32_bf16(af, bf[ks], acc, 0, 0, 0);
        }
        #pragma unroll
        for (int r = 0; r < 4; ++r) {
            int o = ot * 16 + quad * 4 + r;
            size_t oi = ((size_t)b * CC_ + o) * LL_ + l0 + n;
            out[oi] = acc[r] + bo[o] + x[oi];
        }
    }
}

extern "C" void kernel_launch(void* const* d_in, const int* in_sizes, int n_in,
                              void* d_out, int out_size, void* d_ws, size_t ws_size,
                              hipStream_t stream) {
    const float* x  = (const float*)d_in[0];
    const float* g  = (const float*)d_in[1];
    const float* bv = (const float*)d_in[2];
    const float* Wq = (const float*)d_in[3];
    const float* Wk = (const float*)d_in[4];
    const float* Wv = (const float*)d_in[5];
    const float* Wo = (const float*)d_in[6];
    const float* bo = (const float*)d_in[7];
    float* out = (float*)d_out;

    const size_t qkv_elems = (size_t)BB_ * HEADS_ * LL_ * DHEAD_;
    short* q    = (short*)d_ws;
    short* k    = q + qkv_elems;
    short* v    = k + qkv_elems;
    short* ao   = v + qkv_elems;
    short* wqkv = ao + qkv_elems;
    short* wo   = wqkv + 384 * 256;

    k_prep  <<<dim3((384 * 256 + 256 * 128) / 256), dim3(256), 0, stream>>>(Wq, Wk, Wv, Wo, wqkv, wo);
    k_ln_qkv<<<dim3(LL_ / 32, BB_), dim3(512), 0, stream>>>(x, g, bv, wqkv, q, k, v);
    k_attn  <<<dim3(LL_ / 64, BB_ * HEADS_), dim3(512), 0, stream>>>(q, k, v, ao);
    k_oproj <<<dim3(LL_ / 16, 2, BB_), dim3(256), 0, stream>>>(ao, wo, bo, x, out);
}

// Round 11
// 173.562 us; speedup vs baseline: 1.0709x; 1.0709x over previous
//
#include <hip/hip_runtime.h>
#include <math.h>

#define BB_ 8
#define CC_ 256
#define LL_ 2048
#define HEADS_ 4
#define DHEAD_ 32
#define HID_ 128
#define EPS_ 1e-5f
#define SCALE_ 0.17677669529663687f   // 32^-0.5
#define K1_ (SCALE_ * 1.44269504088896f)   // folded into Wq at prep time

typedef short v8s  __attribute__((ext_vector_type(8)));
typedef float v4f  __attribute__((ext_vector_type(4)));
typedef float v16f __attribute__((ext_vector_type(16)));
typedef unsigned v4u __attribute__((ext_vector_type(4)));

__device__ inline short f2bf(float x) {   // RNE f32 -> bf16 bits
    union { float f; unsigned u; } a; a.f = x;
    unsigned r = a.u + 0x7fffu + ((a.u >> 16) & 1u);
    return (short)(r >> 16);
}
__device__ inline unsigned fbits(float x) { union { float f; unsigned u; } a; a.f = x; return a.u; }

// ---------------------------------------------------------------------------
// Kernel 0: weight prep. Blocks 0..383: row o of W' = W*g (q-rows also *K1)
// -> bf16 wqkv[384][256], plus gamma[o] = sum_c W'[o][c], beta[o] = sum_c
// W[o][c]*b[c] (q *K1) -> gb[o] (float2). Blocks 384..511: Wo -> bf16.
// LN affine applied post-GEMM: y = rs*D - (rs*mu)*gamma + beta.
// ---------------------------------------------------------------------------
__global__ __launch_bounds__(256) void k_prep(
    const float* __restrict__ Wq, const float* __restrict__ Wk, const float* __restrict__ Wv,
    const float* __restrict__ Wo, const float* __restrict__ g, const float* __restrict__ bvec,
    short* __restrict__ wqkv, short* __restrict__ wo, float2* __restrict__ gb)
{
    __shared__ float red0[256], red1[256];
    const int blk = blockIdx.x, c = threadIdx.x;
    if (blk < 384) {
        const float* W; int oo; float scale = 1.f;
        if (blk < 128)      { W = Wq; oo = blk;       scale = K1_; }
        else if (blk < 256) { W = Wk; oo = blk - 128; }
        else                { W = Wv; oo = blk - 256; }
        float w  = W[oo * 256 + c] * scale;
        float wg = w * g[c];
        wqkv[blk * 256 + c] = f2bf(wg);
        red0[c] = wg;
        red1[c] = w * bvec[c];
        __syncthreads();
        for (int s = 128; s > 0; s >>= 1) {
            if (c < s) { red0[c] += red0[c + s]; red1[c] += red1[c + s]; }
            __syncthreads();
        }
        if (c == 0) gb[blk] = make_float2(red0[0], red1[0]);
    } else {
        int i2 = (blk - 384) * 256 + c;
        wo[i2] = f2bf(Wo[i2]);
    }
}

// ---------------------------------------------------------------------------
// Kernel 1: LayerNorm-folded QKV projection. Stats fused into the staging
// loop; GEMM on RAW bf16 x; LN affine in the epilogue. Coalesced stores via
// LDS staging. q,k: [B*H, L, 32]; v: [B*H, 32, L] bf16.
// ---------------------------------------------------------------------------
__global__ __launch_bounds__(512) void k_ln_qkv(
    const float* __restrict__ x, const short* __restrict__ wqkv, const float2* __restrict__ gb,
    short* __restrict__ q, short* __restrict__ k, short* __restrict__ v)
{
    __shared__ float xn[CC_ * 33];
    __shared__ short xnT[32 * 264];      // raw bf16 [l][c], later reused as q|k staging
    __shared__ short st2[128 * 48];      // v staging: [o'][l]
    __shared__ float ps_[8 * 32], ps2_[8 * 32];
    __shared__ float rs_s[32], rsmu_s[32];
    const int b   = blockIdx.y;
    const int l0  = blockIdx.x * 32;
    const int tid = threadIdx.x;
    const int wave = tid >> 6, lane = tid & 63;

    // stage + stats in one pass: thread's 16 elements all in column ls
    {
        const int ls = tid & 31;
        float s = 0.f, s2 = 0.f;
        #pragma unroll
        for (int kk = 0; kk < 16; ++kk) {
            int c = (tid >> 5) + 16 * kk;
            float t = x[((size_t)b * CC_ + c) * LL_ + l0 + ls];
            xn[c * 33 + ls] = t;
            s += t; s2 += t * t;
        }
        s  += __shfl_xor(s, 32, 64);
        s2 += __shfl_xor(s2, 32, 64);
        if (lane < 32) { ps_[wave * 32 + lane] = s; ps2_[wave * 32 + lane] = s2; }
    }
    __syncthreads();
    if (tid < 32) {
        float s = 0.f, s2 = 0.f;
        #pragma unroll
        for (int p = 0; p < 8; ++p) { s += ps_[p * 32 + tid]; s2 += ps2_[p * 32 + tid]; }
        float mean = s * (1.f / CC_);
        float var  = s2 * (1.f / CC_) - mean * mean;
        float rs   = rsqrtf(var + EPS_);
        rs_s[tid]   = rs;
        rsmu_s[tid] = rs * mean;
    }
    // transpose raw fp32 -> bf16 [l][c]
    for (int idx = tid; idx < 32 * 128; idx += 512) {
        int ls = idx >> 7, cc = idx & 127;
        int c0 = 2 * cc;
        xnT[ls * 264 + c0]     = f2bf(xn[c0 * 33 + ls]);
        xnT[ls * 264 + c0 + 1] = f2bf(xn[(c0 + 1) * 33 + ls]);
    }
    __syncthreads();

    const int n = lane & 15, quad = lane >> 4;
    const int rowbase = (wave >> 2) * 16;       // 2 row-groups
    const int colbase = (wave & 3) * 96;        // 4 col-groups of 96

    v4f acc[6];
    #pragma unroll
    for (int ct = 0; ct < 6; ++ct) acc[ct] = (v4f){0.f, 0.f, 0.f, 0.f};

    #pragma unroll
    for (int ks = 0; ks < 8; ++ks) {
        const v8s af = *(const v8s*)(xnT + (rowbase + n) * 264 + ks * 32 + quad * 8);
        #pragma unroll
        for (int ct = 0; ct < 6; ++ct) {
            const v8s bfrag = *(const v8s*)(wqkv + (size_t)(colbase + ct * 16 + n) * 256 + ks * 32 + quad * 8);
            acc[ct] = __builtin_amdgcn_mfma_f32_16x16x32_bf16(af, bfrag, acc[ct], 0, 0, 0);
        }
    }
    __syncthreads();   // all waves done reading xnT; safe to reuse as staging

    // epilogue: LN affine + scatter to LDS staging
    float rsv[4], rmv[4];
    #pragma unroll
    for (int r = 0; r < 4; ++r) {
        int l = rowbase + quad * 4 + r;
        rsv[r] = rs_s[l]; rmv[r] = rsmu_s[l];
    }
    #pragma unroll
    for (int ct = 0; ct < 6; ++ct) {
        int o = colbase + ct * 16 + n;
        float2 gbo = gb[o];
        #pragma unroll
        for (int r = 0; r < 4; ++r) {
            int l = rowbase + quad * 4 + r;
            float val = rsv[r] * acc[ct][r] - rmv[r] * gbo.x + gbo.y;
            if (o < 256)      xnT[l * 264 + o] = f2bf(val);
            else              st2[(o - 256) * 48 + l] = f2bf(val);
        }
    }
    __syncthreads();

    {
        int u = tid;
        int h = u >> 7, rest = u & 127;
        int l = rest >> 2, dg = rest & 3;
        size_t bh = (size_t)b * HEADS_ + h;
        v8s qv = *(const v8s*)(xnT + l * 264 + h * 32 + dg * 8);
        *(v8s*)(q + (bh * LL_ + l0 + l) * DHEAD_ + dg * 8) = qv;
        v8s kv = *(const v8s*)(xnT + l * 264 + 128 + h * 32 + dg * 8);
        *(v8s*)(k + (bh * LL_ + l0 + l) * DHEAD_ + dg * 8) = kv;

        int op = u >> 2, lg = u & 3;
        v8s vv = *(const v8s*)(st2 + op * 48 + lg * 8);
        int h2 = op >> 5, d = op & 31;
        *(v8s*)(v + (((size_t)b * HEADS_ + h2) * DHEAD_ + d) * LL_ + l0 + lg * 8) = vv;
    }
}

// ---------------------------------------------------------------------------
// Kernel 2: flash attention, 32x32x16 MFMA, S^T, no max-subtraction.
// r8 structure (512 thr = 4 q-waves x 2 key-halves) + 2-stage S pipeline.
// FIX vs r10: LDV_'s off advances the KEY position (r10 wrongly offset the
// d-row, reading the next head's V for the second PV fragment).
// ---------------------------------------------------------------------------
__global__ __launch_bounds__(512) void k_attn(
    const short* __restrict__ q, const short* __restrict__ k, const short* __restrict__ v,
    short* __restrict__ ao)
{
    __shared__ float Ost[4][32][32];     // [q-wave][q-row][d]
    __shared__ float psumst[4 * 32];
    const int bh   = blockIdx.y;
    const int b    = bh >> 2, h = bh & 3;
    const int tid  = threadIdx.x;
    const int wave = tid >> 6, lane = tid & 63;
    const int wq   = wave & 3;           // q-subtile
    const int kh   = wave >> 2;          // key half: [kh*1024, kh*1024+1024)
    const int m    = lane & 31;
    const int half = lane >> 5;
    const size_t kvbase = (size_t)bh * LL_ * DHEAD_;   // q,k: [bh][l][32]
    const size_t vbase  = (size_t)bh * DHEAD_ * LL_;   // v:   [bh][d][L]

    const int q0 = blockIdx.x * 128 + wq * 32;
    const int kb = kh * 1024;

    const v8s qf0 = *(const v8s*)(q + kvbase + (size_t)(q0 + m) * DHEAD_ + half * 8);
    const v8s qf1 = *(const v8s*)(q + kvbase + (size_t)(q0 + m) * DHEAD_ + 16 + half * 8);

    v16f O = {};
    float psum = 0.f;

    #define LDK_(pos, off) (*(const v8s*)(k + kvbase + (size_t)((pos) + m) * DHEAD_ + (off) + half * 8))
    #define LDV_(pos, off) (*(const v8s*)(v + vbase + (size_t)m * LL_ + (pos) + (off) + half * 8))

    v8s vf0 = LDV_(kb, 0), vf1 = LDV_(kb, 16);
    v8s kn0 = LDK_(kb + 32, 0), kn1 = LDK_(kb + 32, 16);
    v16f S;
    {
        v8s kf0 = LDK_(kb, 0), kf1 = LDK_(kb, 16);
        S = __builtin_amdgcn_mfma_f32_32x32x16_bf16(kf0, qf0, (v16f){}, 0, 0, 0);
        S = __builtin_amdgcn_mfma_f32_32x32x16_bf16(kf1, qf1, S,        0, 0, 0);
    }

    for (int kt = 0; kt < 1024; kt += 32) {
        const int ktn = kb + ((kt + 32) & 1023);   // tile i+1 (wrap: dead on last)
        const int kt2 = kb + ((kt + 64) & 1023);   // tile i+2 K prefetch
        // issue next tile's S-MFMAs first (independent of this tile's VALU)
        v16f Sn = __builtin_amdgcn_mfma_f32_32x32x16_bf16(kn0, qf0, (v16f){}, 0, 0, 0);
        Sn      = __builtin_amdgcn_mfma_f32_32x32x16_bf16(kn1, qf1, Sn,        0, 0, 0);
        kn0 = LDK_(kt2, 0); kn1 = LDK_(kt2, 16);
        v8s vn0 = LDV_(ktn, 0), vn1 = LDV_(ktn, 16);

        // p = exp2(S) (scale folded into Wq); pack key-pairs -> dwords e0..e7
        unsigned e[8];
        #pragma unroll
        for (int i = 0; i < 8; ++i) {
            float pa = __builtin_amdgcn_exp2f(S[2 * i]);
            float pb = __builtin_amdgcn_exp2f(S[2 * i + 1]);
            psum += pa + pb;
            e[i] = __builtin_amdgcn_perm(fbits(pb) + 0x8000u, fbits(pa) + 0x8000u, 0x07060302u);
        }
        // C->A relayout: swap high-half(e_lo) with low-half(e_hi)
        v4u f1, f2;
#if __has_builtin(__builtin_amdgcn_permlane32_swap)
        {
            auto r02 = __builtin_amdgcn_permlane32_swap(e[0], e[2], false, false);
            auto r13 = __builtin_amdgcn_permlane32_swap(e[1], e[3], false, false);
            auto r46 = __builtin_amdgcn_permlane32_swap(e[4], e[6], false, false);
            auto r57 = __builtin_amdgcn_permlane32_swap(e[5], e[7], false, false);
            f1 = (v4u){r02[0], r13[0], r02[1], r13[1]};
            f2 = (v4u){r46[0], r57[0], r46[1], r57[1]};
        }
#else
        {
            unsigned o0 = __shfl_xor(e[0], 32, 64), o1 = __shfl_xor(e[1], 32, 64);
            unsigned o2 = __shfl_xor(e[2], 32, 64), o3 = __shfl_xor(e[3], 32, 64);
            unsigned o4 = __shfl_xor(e[4], 32, 64), o5 = __shfl_xor(e[5], 32, 64);
            unsigned o6 = __shfl_xor(e[6], 32, 64), o7 = __shfl_xor(e[7], 32, 64);
            f1 = half ? (v4u){o2, o3, e[2], e[3]} : (v4u){e[0], e[1], o0, o1};
            f2 = half ? (v4u){o6, o7, e[6], e[7]} : (v4u){e[4], e[5], o4, o5};
        }
#endif
        // PV: O[q][d] += P[q][key] * V[key][d]
        O = __builtin_amdgcn_mfma_f32_32x32x16_bf16(__builtin_bit_cast(v8s, f1), vf0, O, 0, 0, 0);
        O = __builtin_amdgcn_mfma_f32_32x32x16_bf16(__builtin_bit_cast(v8s, f2), vf1, O, 0, 0, 0);

        S = Sn; vf0 = vn0; vf1 = vn1;
    }
    #undef LDK_
    #undef LDV_

    // lane m holds den-partial for q = m after half-combine
    psum += __shfl_xor(psum, 32, 64);

    if (kh == 1) {
        #pragma unroll
        for (int r = 0; r < 16; ++r) {
            int qr = (r & 3) + 8 * (r >> 2) + 4 * half;
            Ost[wq][qr][m] = O[r];
        }
        if (half == 0) psumst[wq * 32 + m] = psum;
    }
    __syncthreads();
    if (kh == 0) {
        float den = psum + psumst[wq * 32 + m];
        float invden = 1.f / den;
        #pragma unroll
        for (int r = 0; r < 16; ++r) {
            int qr = (r & 3) + 8 * (r >> 2) + 4 * half;
            float inv = __shfl(invden, qr, 64);
            float val = (O[r] + Ost[wq][qr][m]) * inv;
            int row = q0 + qr;
            ao[((size_t)b * LL_ + row) * HID_ + h * DHEAD_ + m] = f2bf(val);
        }
    }
}

// ---------------------------------------------------------------------------
// Kernel 3: output projection via MFMA + bias + residual. 16-l x 128-o
// blocks (grid.y = o-half): 2048 blocks -> 8 blocks/CU.
// ---------------------------------------------------------------------------
__global__ __launch_bounds__(256) void k_oproj(
    const short* __restrict__ ao, const short* __restrict__ wo, const float* __restrict__ bo,
    const float* __restrict__ x, float* __restrict__ out)
{
    const int b = blockIdx.z;
    const int l0 = blockIdx.x * 16;
    const int obase = blockIdx.y * 8;            // in 16-o tiles
    const int tid = threadIdx.x;
    const int wave = tid >> 6, lane = tid & 63;
    const int n = lane & 15, quad = lane >> 4;

    v8s bf[4];
    #pragma unroll
    for (int ks = 0; ks < 4; ++ks)
        bf[ks] = *(const v8s*)(ao + ((size_t)b * LL_ + l0 + n) * HID_ + ks * 32 + quad * 8);

    #pragma unroll
    for (int oi_ = 0; oi_ < 2; ++oi_) {
        int ot = obase + wave * 2 + oi_;
        v4f acc = {0.f, 0.f, 0.f, 0.f};
        #pragma unroll
        for (int ks = 0; ks < 4; ++ks) {
            const v8s af = *(const v8s*)(wo + (size_t)(ot * 16 + n) * HID_ + ks * 32 + quad * 8);
            acc = __builtin_amdgcn_mfma_f32_16x16x32_bf16(af, bf[ks], acc, 0, 0, 0);
        }
        #pragma unroll
        for (int r = 0; r < 4; ++r) {
            int o = ot * 16 + quad * 4 + r;
            size_t oi = ((size_t)b * CC_ + o) * LL_ + l0 + n;
            out[oi] = acc[r] + bo[o] + x[oi];
        }
    }
}

extern "C" void kernel_launch(void* const* d_in, const int* in_sizes, int n_in,
                              void* d_out, int out_size, void* d_ws, size_t ws_size,
                              hipStream_t stream) {
    const float* x  = (const float*)d_in[0];
    const float* g  = (const float*)d_in[1];
    const float* bv = (const float*)d_in[2];
    const float* Wq = (const float*)d_in[3];
    const float* Wk = (const float*)d_in[4];
    const float* Wv = (const float*)d_in[5];
    const float* Wo = (const float*)d_in[6];
    const float* bo = (const float*)d_in[7];
    float* out = (float*)d_out;

    const size_t qkv_elems = (size_t)BB_ * HEADS_ * LL_ * DHEAD_;
    short* q    = (short*)d_ws;
    short* k    = q + qkv_elems;
    short* v    = k + qkv_elems;
    short* ao   = v + qkv_elems;
    short* wqkv = ao + qkv_elems;
    short* wo   = wqkv + 384 * 256;
    float2* gb  = (float2*)(wo + 256 * 128);

    k_prep  <<<dim3(512), dim3(256), 0, stream>>>(Wq, Wk, Wv, Wo, g, bv, wqkv, wo, gb);
    k_ln_qkv<<<dim3(LL_ / 32, BB_), dim3(512), 0, stream>>>(x, wqkv, gb, q, k, v);
    k_attn  <<<dim3(LL_ / 128, BB_ * HEADS_), dim3(512), 0, stream>>>(q, k, v, ao);
    k_oproj <<<dim3(LL_ / 16, 2, BB_), dim3(256), 0, stream>>>(ao, wo, bo, x, out);
}

// Round 12
// 171.127 us; speedup vs baseline: 1.0861x; 1.0142x over previous
//
#include <hip/hip_runtime.h>
#include <math.h>

#define BB_ 8
#define CC_ 256
#define LL_ 2048
#define HEADS_ 4
#define DHEAD_ 32
#define HID_ 128
#define EPS_ 1e-5f
#define SCALE_ 0.17677669529663687f   // 32^-0.5
#define K1_ (SCALE_ * 1.44269504088896f)   // folded into Wq at prep time

typedef short v8s  __attribute__((ext_vector_type(8)));
typedef float v4f  __attribute__((ext_vector_type(4)));
typedef float v16f __attribute__((ext_vector_type(16)));
typedef unsigned v4u __attribute__((ext_vector_type(4)));

__device__ inline short f2bf(float x) {   // RNE f32 -> bf16 bits
    union { float f; unsigned u; } a; a.f = x;
    unsigned r = a.u + 0x7fffu + ((a.u >> 16) & 1u);
    return (short)(r >> 16);
}
__device__ inline unsigned fbits(float x) { union { float f; unsigned u; } a; a.f = x; return a.u; }

// ---------------------------------------------------------------------------
// Kernel 0: weight prep. Blocks 0..383: row o of W' = W*g (q-rows also *K1)
// -> bf16 wqkv[384][256], plus gamma[o] = sum_c W'[o][c], beta[o] = sum_c
// W[o][c]*b[c] -> gb[o]. Blocks 384..511: Wo -> bf16.
// LN affine applied post-GEMM: y = rs*D - (rs*mu)*gamma + beta.
// ---------------------------------------------------------------------------
__global__ __launch_bounds__(256) void k_prep(
    const float* __restrict__ Wq, const float* __restrict__ Wk, const float* __restrict__ Wv,
    const float* __restrict__ Wo, const float* __restrict__ g, const float* __restrict__ bvec,
    short* __restrict__ wqkv, short* __restrict__ wo, float2* __restrict__ gb)
{
    __shared__ float red0[256], red1[256];
    const int blk = blockIdx.x, c = threadIdx.x;
    if (blk < 384) {
        const float* W; int oo; float scale = 1.f;
        if (blk < 128)      { W = Wq; oo = blk;       scale = K1_; }
        else if (blk < 256) { W = Wk; oo = blk - 128; }
        else                { W = Wv; oo = blk - 256; }
        float w  = W[oo * 256 + c] * scale;
        float wg = w * g[c];
        wqkv[blk * 256 + c] = f2bf(wg);
        red0[c] = wg;
        red1[c] = w * bvec[c];
        __syncthreads();
        for (int s = 128; s > 0; s >>= 1) {
            if (c < s) { red0[c] += red0[c + s]; red1[c] += red1[c + s]; }
            __syncthreads();
        }
        if (c == 0) gb[blk] = make_float2(red0[0], red1[0]);
    } else {
        int i2 = (blk - 384) * 256 + c;
        wo[i2] = f2bf(Wo[i2]);
    }
}

// ---------------------------------------------------------------------------
// Kernel 1: LayerNorm-folded QKV projection (unchanged r11).
// ---------------------------------------------------------------------------
__global__ __launch_bounds__(512) void k_ln_qkv(
    const float* __restrict__ x, const short* __restrict__ wqkv, const float2* __restrict__ gb,
    short* __restrict__ q, short* __restrict__ k, short* __restrict__ v)
{
    __shared__ float xn[CC_ * 33];
    __shared__ short xnT[32 * 264];      // raw bf16 [l][c], later reused as q|k staging
    __shared__ short st2[128 * 48];      // v staging: [o'][l]
    __shared__ float ps_[8 * 32], ps2_[8 * 32];
    __shared__ float rs_s[32], rsmu_s[32];
    const int b   = blockIdx.y;
    const int l0  = blockIdx.x * 32;
    const int tid = threadIdx.x;
    const int wave = tid >> 6, lane = tid & 63;

    {
        const int ls = tid & 31;
        float s = 0.f, s2 = 0.f;
        #pragma unroll
        for (int kk = 0; kk < 16; ++kk) {
            int c = (tid >> 5) + 16 * kk;
            float t = x[((size_t)b * CC_ + c) * LL_ + l0 + ls];
            xn[c * 33 + ls] = t;
            s += t; s2 += t * t;
        }
        s  += __shfl_xor(s, 32, 64);
        s2 += __shfl_xor(s2, 32, 64);
        if (lane < 32) { ps_[wave * 32 + lane] = s; ps2_[wave * 32 + lane] = s2; }
    }
    __syncthreads();
    if (tid < 32) {
        float s = 0.f, s2 = 0.f;
        #pragma unroll
        for (int p = 0; p < 8; ++p) { s += ps_[p * 32 + tid]; s2 += ps2_[p * 32 + tid]; }
        float mean = s * (1.f / CC_);
        float var  = s2 * (1.f / CC_) - mean * mean;
        float rs   = rsqrtf(var + EPS_);
        rs_s[tid]   = rs;
        rsmu_s[tid] = rs * mean;
    }
    for (int idx = tid; idx < 32 * 128; idx += 512) {
        int ls = idx >> 7, cc = idx & 127;
        int c0 = 2 * cc;
        xnT[ls * 264 + c0]     = f2bf(xn[c0 * 33 + ls]);
        xnT[ls * 264 + c0 + 1] = f2bf(xn[(c0 + 1) * 33 + ls]);
    }
    __syncthreads();

    const int n = lane & 15, quad = lane >> 4;
    const int rowbase = (wave >> 2) * 16;
    const int colbase = (wave & 3) * 96;

    v4f acc[6];
    #pragma unroll
    for (int ct = 0; ct < 6; ++ct) acc[ct] = (v4f){0.f, 0.f, 0.f, 0.f};

    #pragma unroll
    for (int ks = 0; ks < 8; ++ks) {
        const v8s af = *(const v8s*)(xnT + (rowbase + n) * 264 + ks * 32 + quad * 8);
        #pragma unroll
        for (int ct = 0; ct < 6; ++ct) {
            const v8s bfrag = *(const v8s*)(wqkv + (size_t)(colbase + ct * 16 + n) * 256 + ks * 32 + quad * 8);
            acc[ct] = __builtin_amdgcn_mfma_f32_16x16x32_bf16(af, bfrag, acc[ct], 0, 0, 0);
        }
    }
    __syncthreads();

    float rsv[4], rmv[4];
    #pragma unroll
    for (int r = 0; r < 4; ++r) {
        int l = rowbase + quad * 4 + r;
        rsv[r] = rs_s[l]; rmv[r] = rsmu_s[l];
    }
    #pragma unroll
    for (int ct = 0; ct < 6; ++ct) {
        int o = colbase + ct * 16 + n;
        float2 gbo = gb[o];
        #pragma unroll
        for (int r = 0; r < 4; ++r) {
            int l = rowbase + quad * 4 + r;
            float val = rsv[r] * acc[ct][r] - rmv[r] * gbo.x + gbo.y;
            if (o < 256)      xnT[l * 264 + o] = f2bf(val);
            else              st2[(o - 256) * 48 + l] = f2bf(val);
        }
    }
    __syncthreads();

    {
        int u = tid;
        int h = u >> 7, rest = u & 127;
        int l = rest >> 2, dg = rest & 3;
        size_t bh = (size_t)b * HEADS_ + h;
        v8s qv = *(const v8s*)(xnT + l * 264 + h * 32 + dg * 8);
        *(v8s*)(q + (bh * LL_ + l0 + l) * DHEAD_ + dg * 8) = qv;
        v8s kv = *(const v8s*)(xnT + l * 264 + 128 + h * 32 + dg * 8);
        *(v8s*)(k + (bh * LL_ + l0 + l) * DHEAD_ + dg * 8) = kv;

        int op = u >> 2, lg = u & 3;
        v8s vv = *(const v8s*)(st2 + op * 48 + lg * 8);
        int h2 = op >> 5, d = op & 31;
        *(v8s*)(v + (((size_t)b * HEADS_ + h2) * DHEAD_ + d) * LL_ + l0 + lg * 8) = vv;
    }
}

// ---------------------------------------------------------------------------
// Kernel 2: flash attention, 32x32x16 MFMA, S^T, no max-subtraction.
// r8 decomposition (512 thr = 4 q-waves x 2 key-halves) with the key-loop
// unrolled x2 into TWO INDEPENDENT tile streams (A: keys kt..kt+31,
// B: kt+32..kt+63): separate K/V prefetch, separate exp/pack/relayout —
// the scheduler interleaves two chains, halving latency stalls.
// ---------------------------------------------------------------------------
__global__ __launch_bounds__(512) void k_attn(
    const short* __restrict__ q, const short* __restrict__ k, const short* __restrict__ v,
    short* __restrict__ ao)
{
    __shared__ float Ost[4][32][32];     // [q-wave][q-row][d]
    __shared__ float psumst[4 * 32];
    const int bh   = blockIdx.y;
    const int b    = bh >> 2, h = bh & 3;
    const int tid  = threadIdx.x;
    const int wave = tid >> 6, lane = tid & 63;
    const int wq   = wave & 3;           // q-subtile
    const int kh   = wave >> 2;          // key half: [kh*1024, kh*1024+1024)
    const int m    = lane & 31;
    const int half = lane >> 5;
    const size_t kvbase = (size_t)bh * LL_ * DHEAD_;   // q,k: [bh][l][32]
    const size_t vbase  = (size_t)bh * DHEAD_ * LL_;   // v:   [bh][d][L]

    const int q0 = blockIdx.x * 128 + wq * 32;
    const int kb = kh * 1024;

    const v8s qf0 = *(const v8s*)(q + kvbase + (size_t)(q0 + m) * DHEAD_ + half * 8);
    const v8s qf1 = *(const v8s*)(q + kvbase + (size_t)(q0 + m) * DHEAD_ + 16 + half * 8);

    v16f O = {};
    float psumA = 0.f, psumB = 0.f;

    #define LDK_(pos, off) (*(const v8s*)(k + kvbase + (size_t)((pos) + m) * DHEAD_ + (off) + half * 8))
    #define LDV_(pos, off) (*(const v8s*)(v + vbase + (size_t)m * LL_ + (pos) + (off) + half * 8))

    // stream A = tiles kt, stream B = tiles kt+32
    v8s kA0 = LDK_(kb, 0),      kA1 = LDK_(kb, 16);
    v8s kB0 = LDK_(kb + 32, 0), kB1 = LDK_(kb + 32, 16);
    v8s vA0 = LDV_(kb, 0),      vA1 = LDV_(kb, 16);
    v8s vB0 = LDV_(kb + 32, 0), vB1 = LDV_(kb + 32, 16);

    for (int kt = 0; kt < 1024; kt += 64) {
        // both S tiles first (independent MFMA streams)
        v16f SA = __builtin_amdgcn_mfma_f32_32x32x16_bf16(kA0, qf0, (v16f){}, 0, 0, 0);
        SA      = __builtin_amdgcn_mfma_f32_32x32x16_bf16(kA1, qf1, SA,        0, 0, 0);
        v16f SB = __builtin_amdgcn_mfma_f32_32x32x16_bf16(kB0, qf0, (v16f){}, 0, 0, 0);
        SB      = __builtin_amdgcn_mfma_f32_32x32x16_bf16(kB1, qf1, SB,        0, 0, 0);

        // prefetch next pair (wrap within own half; dead on last iter)
        const int pA = kb + ((kt + 64) & 1023);
        const int pB = kb + ((kt + 96) & 1023);
        v8s kA0n = LDK_(pA, 0), kA1n = LDK_(pA, 16);
        v8s kB0n = LDK_(pB, 0), kB1n = LDK_(pB, 16);
        v8s vA0n = LDV_(pA, 0), vA1n = LDV_(pA, 16);
        v8s vB0n = LDV_(pB, 0), vB1n = LDV_(pB, 16);

        // two independent exp/pack/relayout streams
        unsigned eA[8], eB[8];
        #pragma unroll
        for (int i = 0; i < 8; ++i) {
            float a0 = __builtin_amdgcn_exp2f(SA[2 * i]);
            float a1 = __builtin_amdgcn_exp2f(SA[2 * i + 1]);
            psumA += a0 + a1;
            eA[i] = __builtin_amdgcn_perm(fbits(a1) + 0x8000u, fbits(a0) + 0x8000u, 0x07060302u);
            float b0 = __builtin_amdgcn_exp2f(SB[2 * i]);
            float b1 = __builtin_amdgcn_exp2f(SB[2 * i + 1]);
            psumB += b0 + b1;
            eB[i] = __builtin_amdgcn_perm(fbits(b1) + 0x8000u, fbits(b0) + 0x8000u, 0x07060302u);
        }
        v4u f1A, f2A, f1B, f2B;
#if __has_builtin(__builtin_amdgcn_permlane32_swap)
        {
            auto a02 = __builtin_amdgcn_permlane32_swap(eA[0], eA[2], false, false);
            auto a13 = __builtin_amdgcn_permlane32_swap(eA[1], eA[3], false, false);
            auto a46 = __builtin_amdgcn_permlane32_swap(eA[4], eA[6], false, false);
            auto a57 = __builtin_amdgcn_permlane32_swap(eA[5], eA[7], false, false);
            f1A = (v4u){a02[0], a13[0], a02[1], a13[1]};
            f2A = (v4u){a46[0], a57[0], a46[1], a57[1]};
            auto b02 = __builtin_amdgcn_permlane32_swap(eB[0], eB[2], false, false);
            auto b13 = __builtin_amdgcn_permlane32_swap(eB[1], eB[3], false, false);
            auto b46 = __builtin_amdgcn_permlane32_swap(eB[4], eB[6], false, false);
            auto b57 = __builtin_amdgcn_permlane32_swap(eB[5], eB[7], false, false);
            f1B = (v4u){b02[0], b13[0], b02[1], b13[1]};
            f2B = (v4u){b46[0], b57[0], b46[1], b57[1]};
        }
#else
        {
            unsigned o0 = __shfl_xor(eA[0], 32, 64), o1 = __shfl_xor(eA[1], 32, 64);
            unsigned o2 = __shfl_xor(eA[2], 32, 64), o3 = __shfl_xor(eA[3], 32, 64);
            unsigned o4 = __shfl_xor(eA[4], 32, 64), o5 = __shfl_xor(eA[5], 32, 64);
            unsigned o6 = __shfl_xor(eA[6], 32, 64), o7 = __shfl_xor(eA[7], 32, 64);
            f1A = half ? (v4u){o2, o3, eA[2], eA[3]} : (v4u){eA[0], eA[1], o0, o1};
            f2A = half ? (v4u){o6, o7, eA[6], eA[7]} : (v4u){eA[4], eA[5], o4, o5};
            unsigned p0 = __shfl_xor(eB[0], 32, 64), p1 = __shfl_xor(eB[1], 32, 64);
            unsigned p2 = __shfl_xor(eB[2], 32, 64), p3 = __shfl_xor(eB[3], 32, 64);
            unsigned p4 = __shfl_xor(eB[4], 32, 64), p5 = __shfl_xor(eB[5], 32, 64);
            unsigned p6 = __shfl_xor(eB[6], 32, 64), p7 = __shfl_xor(eB[7], 32, 64);
            f1B = half ? (v4u){p2, p3, eB[2], eB[3]} : (v4u){eB[0], eB[1], p0, p1};
            f2B = half ? (v4u){p6, p7, eB[6], eB[7]} : (v4u){eB[4], eB[5], p4, p5};
        }
#endif
        // PV for both tiles
        O = __builtin_amdgcn_mfma_f32_32x32x16_bf16(__builtin_bit_cast(v8s, f1A), vA0, O, 0, 0, 0);
        O = __builtin_amdgcn_mfma_f32_32x32x16_bf16(__builtin_bit_cast(v8s, f2A), vA1, O, 0, 0, 0);
        O = __builtin_amdgcn_mfma_f32_32x32x16_bf16(__builtin_bit_cast(v8s, f1B), vB0, O, 0, 0, 0);
        O = __builtin_amdgcn_mfma_f32_32x32x16_bf16(__builtin_bit_cast(v8s, f2B), vB1, O, 0, 0, 0);

        kA0 = kA0n; kA1 = kA1n; kB0 = kB0n; kB1 = kB1n;
        vA0 = vA0n; vA1 = vA1n; vB0 = vB0n; vB1 = vB1n;
    }
    #undef LDK_
    #undef LDV_

    float psum = psumA + psumB;
    psum += __shfl_xor(psum, 32, 64);    // lane m: den-partial for q = m

    if (kh == 1) {
        #pragma unroll
        for (int r = 0; r < 16; ++r) {
            int qr = (r & 3) + 8 * (r >> 2) + 4 * half;
            Ost[wq][qr][m] = O[r];
        }
        if (half == 0) psumst[wq * 32 + m] = psum;
    }
    __syncthreads();
    if (kh == 0) {
        float den = psum + psumst[wq * 32 + m];
        float invden = 1.f / den;
        #pragma unroll
        for (int r = 0; r < 16; ++r) {
            int qr = (r & 3) + 8 * (r >> 2) + 4 * half;
            float inv = __shfl(invden, qr, 64);
            float val = (O[r] + Ost[wq][qr][m]) * inv;
            int row = q0 + qr;
            ao[((size_t)b * LL_ + row) * HID_ + h * DHEAD_ + m] = f2bf(val);
        }
    }
}

// ---------------------------------------------------------------------------
// Kernel 3: output projection via MFMA + bias + residual (unchanged r11).
// ---------------------------------------------------------------------------
__global__ __launch_bounds__(256) void k_oproj(
    const short* __restrict__ ao, const short* __restrict__ wo, const float* __restrict__ bo,
    const float* __restrict__ x, float* __restrict__ out)
{
    const int b = blockIdx.z;
    const int l0 = blockIdx.x * 16;
    const int obase = blockIdx.y * 8;            // in 16-o tiles
    const int tid = threadIdx.x;
    const int wave = tid >> 6, lane = tid & 63;
    const int n = lane & 15, quad = lane >> 4;

    v8s bf[4];
    #pragma unroll
    for (int ks = 0; ks < 4; ++ks)
        bf[ks] = *(const v8s*)(ao + ((size_t)b * LL_ + l0 + n) * HID_ + ks * 32 + quad * 8);

    #pragma unroll
    for (int oi_ = 0; oi_ < 2; ++oi_) {
        int ot = obase + wave * 2 + oi_;
        v4f acc = {0.f, 0.f, 0.f, 0.f};
        #pragma unroll
        for (int ks = 0; ks < 4; ++ks) {
            const v8s af = *(const v8s*)(wo + (size_t)(ot * 16 + n) * HID_ + ks * 32 + quad * 8);
            acc = __builtin_amdgcn_mfma_f32_16x16x32_bf16(af, bf[ks], acc, 0, 0, 0);
        }
        #pragma unroll
        for (int r = 0; r < 4; ++r) {
            int o = ot * 16 + quad * 4 + r;
            size_t oi = ((size_t)b * CC_ + o) * LL_ + l0 + n;
            out[oi] = acc[r] + bo[o] + x[oi];
        }
    }
}

extern "C" void kernel_launch(void* const* d_in, const int* in_sizes, int n_in,
                              void* d_out, int out_size, void* d_ws, size_t ws_size,
                              hipStream_t stream) {
    const float* x  = (const float*)d_in[0];
    const float* g  = (const float*)d_in[1];
    const float* bv = (const float*)d_in[2];
    const float* Wq = (const float*)d_in[3];
    const float* Wk = (const float*)d_in[4];
    const float* Wv = (const float*)d_in[5];
    const float* Wo = (const float*)d_in[6];
    const float* bo = (const float*)d_in[7];
    float* out = (float*)d_out;

    const size_t qkv_elems = (size_t)BB_ * HEADS_ * LL_ * DHEAD_;
    short* q    = (short*)d_ws;
    short* k    = q + qkv_elems;
    short* v    = k + qkv_elems;
    short* ao   = v + qkv_elems;
    short* wqkv = ao + qkv_elems;
    short* wo   = wqkv + 384 * 256;
    float2* gb  = (float2*)(wo + 256 * 128);

    k_prep  <<<dim3(512), dim3(256), 0, stream>>>(Wq, Wk, Wv, Wo, g, bv, wqkv, wo, gb);
    k_ln_qkv<<<dim3(LL_ / 32, BB_), dim3(512), 0, stream>>>(x, wqkv, gb, q, k, v);
    k_attn  <<<dim3(LL_ / 128, BB_ * HEADS_), dim3(512), 0, stream>>>(q, k, v, ao);
    k_oproj <<<dim3(LL_ / 16, 2, BB_), dim3(256), 0, stream>>>(ao, wo, bo, x, out);
}

// Round 13
// 166.683 us; speedup vs baseline: 1.1151x; 1.0267x over previous
//
#include <hip/hip_runtime.h>
#include <math.h>

#define BB_ 8
#define CC_ 256
#define LL_ 2048
#define HEADS_ 4
#define DHEAD_ 32
#define HID_ 128
#define EPS_ 1e-5f
#define SCALE_ 0.17677669529663687f   // 32^-0.5
#define K1_ (SCALE_ * 1.44269504088896f)   // folded into Wq at prep time

typedef short v8s  __attribute__((ext_vector_type(8)));
typedef float v4f  __attribute__((ext_vector_type(4)));
typedef float v16f __attribute__((ext_vector_type(16)));
typedef unsigned v4u __attribute__((ext_vector_type(4)));

__device__ inline short f2bf(float x) {   // RNE f32 -> bf16 bits
    union { float f; unsigned u; } a; a.f = x;
    unsigned r = a.u + 0x7fffu + ((a.u >> 16) & 1u);
    return (short)(r >> 16);
}
__device__ inline unsigned fbits(float x) { union { float f; unsigned u; } a; a.f = x; return a.u; }

// ---------------------------------------------------------------------------
// Kernel 0: weight prep (unchanged r12).
// ---------------------------------------------------------------------------
__global__ __launch_bounds__(256) void k_prep(
    const float* __restrict__ Wq, const float* __restrict__ Wk, const float* __restrict__ Wv,
    const float* __restrict__ Wo, const float* __restrict__ g, const float* __restrict__ bvec,
    short* __restrict__ wqkv, short* __restrict__ wo, float2* __restrict__ gb)
{
    __shared__ float red0[256], red1[256];
    const int blk = blockIdx.x, c = threadIdx.x;
    if (blk < 384) {
        const float* W; int oo; float scale = 1.f;
        if (blk < 128)      { W = Wq; oo = blk;       scale = K1_; }
        else if (blk < 256) { W = Wk; oo = blk - 128; }
        else                { W = Wv; oo = blk - 256; }
        float w  = W[oo * 256 + c] * scale;
        float wg = w * g[c];
        wqkv[blk * 256 + c] = f2bf(wg);
        red0[c] = wg;
        red1[c] = w * bvec[c];
        __syncthreads();
        for (int s = 128; s > 0; s >>= 1) {
            if (c < s) { red0[c] += red0[c + s]; red1[c] += red1[c + s]; }
            __syncthreads();
        }
        if (c == 0) gb[blk] = make_float2(red0[0], red1[0]);
    } else {
        int i2 = (blk - 384) * 256 + c;
        wo[i2] = f2bf(Wo[i2]);
    }
}

// ---------------------------------------------------------------------------
// Kernel 1: LayerNorm-folded QKV projection (unchanged r12).
// ---------------------------------------------------------------------------
__global__ __launch_bounds__(512) void k_ln_qkv(
    const float* __restrict__ x, const short* __restrict__ wqkv, const float2* __restrict__ gb,
    short* __restrict__ q, short* __restrict__ k, short* __restrict__ v)
{
    __shared__ float xn[CC_ * 33];
    __shared__ short xnT[32 * 264];
    __shared__ short st2[128 * 48];
    __shared__ float ps_[8 * 32], ps2_[8 * 32];
    __shared__ float rs_s[32], rsmu_s[32];
    const int b   = blockIdx.y;
    const int l0  = blockIdx.x * 32;
    const int tid = threadIdx.x;
    const int wave = tid >> 6, lane = tid & 63;

    {
        const int ls = tid & 31;
        float s = 0.f, s2 = 0.f;
        #pragma unroll
        for (int kk = 0; kk < 16; ++kk) {
            int c = (tid >> 5) + 16 * kk;
            float t = x[((size_t)b * CC_ + c) * LL_ + l0 + ls];
            xn[c * 33 + ls] = t;
            s += t; s2 += t * t;
        }
        s  += __shfl_xor(s, 32, 64);
        s2 += __shfl_xor(s2, 32, 64);
        if (lane < 32) { ps_[wave * 32 + lane] = s; ps2_[wave * 32 + lane] = s2; }
    }
    __syncthreads();
    if (tid < 32) {
        float s = 0.f, s2 = 0.f;
        #pragma unroll
        for (int p = 0; p < 8; ++p) { s += ps_[p * 32 + tid]; s2 += ps2_[p * 32 + tid]; }
        float mean = s * (1.f / CC_);
        float var  = s2 * (1.f / CC_) - mean * mean;
        float rs   = rsqrtf(var + EPS_);
        rs_s[tid]   = rs;
        rsmu_s[tid] = rs * mean;
    }
    for (int idx = tid; idx < 32 * 128; idx += 512) {
        int ls = idx >> 7, cc = idx & 127;
        int c0 = 2 * cc;
        xnT[ls * 264 + c0]     = f2bf(xn[c0 * 33 + ls]);
        xnT[ls * 264 + c0 + 1] = f2bf(xn[(c0 + 1) * 33 + ls]);
    }
    __syncthreads();

    const int n = lane & 15, quad = lane >> 4;
    const int rowbase = (wave >> 2) * 16;
    const int colbase = (wave & 3) * 96;

    v4f acc[6];
    #pragma unroll
    for (int ct = 0; ct < 6; ++ct) acc[ct] = (v4f){0.f, 0.f, 0.f, 0.f};

    #pragma unroll
    for (int ks = 0; ks < 8; ++ks) {
        const v8s af = *(const v8s*)(xnT + (rowbase + n) * 264 + ks * 32 + quad * 8);
        #pragma unroll
        for (int ct = 0; ct < 6; ++ct) {
            const v8s bfrag = *(const v8s*)(wqkv + (size_t)(colbase + ct * 16 + n) * 256 + ks * 32 + quad * 8);
            acc[ct] = __builtin_amdgcn_mfma_f32_16x16x32_bf16(af, bfrag, acc[ct], 0, 0, 0);
        }
    }
    __syncthreads();

    float rsv[4], rmv[4];
    #pragma unroll
    for (int r = 0; r < 4; ++r) {
        int l = rowbase + quad * 4 + r;
        rsv[r] = rs_s[l]; rmv[r] = rsmu_s[l];
    }
    #pragma unroll
    for (int ct = 0; ct < 6; ++ct) {
        int o = colbase + ct * 16 + n;
        float2 gbo = gb[o];
        #pragma unroll
        for (int r = 0; r < 4; ++r) {
            int l = rowbase + quad * 4 + r;
            float val = rsv[r] * acc[ct][r] - rmv[r] * gbo.x + gbo.y;
            if (o < 256)      xnT[l * 264 + o] = f2bf(val);
            else              st2[(o - 256) * 48 + l] = f2bf(val);
        }
    }
    __syncthreads();

    {
        int u = tid;
        int h = u >> 7, rest = u & 127;
        int l = rest >> 2, dg = rest & 3;
        size_t bh = (size_t)b * HEADS_ + h;
        v8s qv = *(const v8s*)(xnT + l * 264 + h * 32 + dg * 8);
        *(v8s*)(q + (bh * LL_ + l0 + l) * DHEAD_ + dg * 8) = qv;
        v8s kv = *(const v8s*)(xnT + l * 264 + 128 + h * 32 + dg * 8);
        *(v8s*)(k + (bh * LL_ + l0 + l) * DHEAD_ + dg * 8) = kv;

        int op = u >> 2, lg = u & 3;
        v8s vv = *(const v8s*)(st2 + op * 48 + lg * 8);
        int h2 = op >> 5, d = op & 31;
        *(v8s*)(v + (((size_t)b * HEADS_ + h2) * DHEAD_ + d) * LL_ + l0 + lg * 8) = vv;
    }
}

// ---------------------------------------------------------------------------
// Kernel 2: flash attention, 32x32x16 MFMA, S^T, no max-subtraction.
// RESTRUCTURED: 256 thr = 4 q-waves x 32 q, each wave spans ALL 2048 keys
// (no split-K, no LDS combine). K/V staged cooperatively per 256-key chunk
// into LDS (once per block, not per wave): inner loop reads only LDS ->
// short dependency chains; barriers only 2/chunk. K rows padded to 40
// halves, V rows to 264 halves (16B-aligned b128, worst 4-way banks).
// ---------------------------------------------------------------------------
#define CHK_ 256                         // keys per staged chunk
__global__ __launch_bounds__(256) void k_attn(
    const short* __restrict__ q, const short* __restrict__ k, const short* __restrict__ v,
    short* __restrict__ ao)
{
    __shared__ short Kb[CHK_ * 40];      // [key][d pad40]
    __shared__ short Vb[32 * 264];       // [d][key pad264]
    const int bh   = blockIdx.y;
    const int b    = bh >> 2, h = bh & 3;
    const int tid  = threadIdx.x;
    const int wave = tid >> 6, lane = tid & 63;
    const int m    = lane & 31;
    const int half = lane >> 5;
    const size_t kvbase = (size_t)bh * LL_ * DHEAD_;   // q,k: [bh][l][32]
    const size_t vbase  = (size_t)bh * DHEAD_ * LL_;   // v:   [bh][d][L]

    const int q0 = blockIdx.x * 128 + wave * 32;

    // persistent Q B-frags: B[k=d][n=q]
    const v8s qf0 = *(const v8s*)(q + kvbase + (size_t)(q0 + m) * DHEAD_ + half * 8);
    const v8s qf1 = *(const v8s*)(q + kvbase + (size_t)(q0 + m) * DHEAD_ + 16 + half * 8);

    v16f O = {};
    float psum = 0.f;

    for (int kc = 0; kc < LL_; kc += CHK_) {
        __syncthreads();   // previous chunk's readers done before overwrite
        // --- stage K: thread t -> key row t (64B = 4 x 16B) ---
        {
            const short* src = k + kvbase + (size_t)(kc + tid) * DHEAD_;
            short* dst = Kb + tid * 40;
            #pragma unroll
            for (int j = 0; j < 4; ++j)
                *(v8s*)(dst + j * 8) = *(const v8s*)(src + j * 8);
        }
        // --- stage V: pass p -> rows d = p*8 + (t>>5), 16B per lane ---
        {
            const int col = (tid & 31) * 8, dr = tid >> 5;
            #pragma unroll
            for (int p = 0; p < 4; ++p) {
                int d = p * 8 + dr;
                *(v8s*)(Vb + d * 264 + col) =
                    *(const v8s*)(v + vbase + (size_t)d * LL_ + kc + col);
            }
        }
        __syncthreads();   // staging visible to all waves

        // --- compute 8 key-tiles of 32 from LDS ---
        #pragma unroll
        for (int ktl = 0; ktl < CHK_; ktl += 32) {
            const v8s kf0 = *(const v8s*)(Kb + (ktl + m) * 40 + half * 8);
            const v8s kf1 = *(const v8s*)(Kb + (ktl + m) * 40 + 16 + half * 8);
            v16f S = __builtin_amdgcn_mfma_f32_32x32x16_bf16(kf0, qf0, (v16f){}, 0, 0, 0);
            S      = __builtin_amdgcn_mfma_f32_32x32x16_bf16(kf1, qf1, S,        0, 0, 0);

            const v8s vf0 = *(const v8s*)(Vb + m * 264 + ktl + half * 8);
            const v8s vf1 = *(const v8s*)(Vb + m * 264 + ktl + 16 + half * 8);

            // p = exp2(S) (scale folded into Wq); pack key-pairs -> e0..e7
            unsigned e[8];
            #pragma unroll
            for (int i = 0; i < 8; ++i) {
                float pa = __builtin_amdgcn_exp2f(S[2 * i]);
                float pb = __builtin_amdgcn_exp2f(S[2 * i + 1]);
                psum += pa + pb;
                e[i] = __builtin_amdgcn_perm(fbits(pb) + 0x8000u, fbits(pa) + 0x8000u, 0x07060302u);
            }
            // C->A relayout: swap high-half(e_lo) with low-half(e_hi)
            v4u f1, f2;
#if __has_builtin(__builtin_amdgcn_permlane32_swap)
            {
                auto r02 = __builtin_amdgcn_permlane32_swap(e[0], e[2], false, false);
                auto r13 = __builtin_amdgcn_permlane32_swap(e[1], e[3], false, false);
                auto r46 = __builtin_amdgcn_permlane32_swap(e[4], e[6], false, false);
                auto r57 = __builtin_amdgcn_permlane32_swap(e[5], e[7], false, false);
                f1 = (v4u){r02[0], r13[0], r02[1], r13[1]};
                f2 = (v4u){r46[0], r57[0], r46[1], r57[1]};
            }
#else
            {
                unsigned o0 = __shfl_xor(e[0], 32, 64), o1 = __shfl_xor(e[1], 32, 64);
                unsigned o2 = __shfl_xor(e[2], 32, 64), o3 = __shfl_xor(e[3], 32, 64);
                unsigned o4 = __shfl_xor(e[4], 32, 64), o5 = __shfl_xor(e[5], 32, 64);
                unsigned o6 = __shfl_xor(e[6], 32, 64), o7 = __shfl_xor(e[7], 32, 64);
                f1 = half ? (v4u){o2, o3, e[2], e[3]} : (v4u){e[0], e[1], o0, o1};
                f2 = half ? (v4u){o6, o7, e[6], e[7]} : (v4u){e[4], e[5], o4, o5};
            }
#endif
            // PV: O[q][d] += P[q][key] * V[key][d]
            O = __builtin_amdgcn_mfma_f32_32x32x16_bf16(__builtin_bit_cast(v8s, f1), vf0, O, 0, 0, 0);
            O = __builtin_amdgcn_mfma_f32_32x32x16_bf16(__builtin_bit_cast(v8s, f2), vf1, O, 0, 0, 0);
        }
    }

    // lane m holds den-partial for q = m after half-combine; no cross-wave combine
    psum += __shfl_xor(psum, 32, 64);
    float invden = 1.f / psum;
    #pragma unroll
    for (int r = 0; r < 16; ++r) {
        int qr = (r & 3) + 8 * (r >> 2) + 4 * half;
        float inv = __shfl(invden, qr, 64);
        int row = q0 + qr;
        ao[((size_t)b * LL_ + row) * HID_ + h * DHEAD_ + m] = f2bf(O[r] * inv);
    }
}

// ---------------------------------------------------------------------------
// Kernel 3: output projection via MFMA + bias + residual (unchanged r12).
// ---------------------------------------------------------------------------
__global__ __launch_bounds__(256) void k_oproj(
    const short* __restrict__ ao, const short* __restrict__ wo, const float* __restrict__ bo,
    const float* __restrict__ x, float* __restrict__ out)
{
    const int b = blockIdx.z;
    const int l0 = blockIdx.x * 16;
    const int obase = blockIdx.y * 8;            // in 16-o tiles
    const int tid = threadIdx.x;
    const int wave = tid >> 6, lane = tid & 63;
    const int n = lane & 15, quad = lane >> 4;

    v8s bf[4];
    #pragma unroll
    for (int ks = 0; ks < 4; ++ks)
        bf[ks] = *(const v8s*)(ao + ((size_t)b * LL_ + l0 + n) * HID_ + ks * 32 + quad * 8);

    #pragma unroll
    for (int oi_ = 0; oi_ < 2; ++oi_) {
        int ot = obase + wave * 2 + oi_;
        v4f acc = {0.f, 0.f, 0.f, 0.f};
        #pragma unroll
        for (int ks = 0; ks < 4; ++ks) {
            const v8s af = *(const v8s*)(wo + (size_t)(ot * 16 + n) * HID_ + ks * 32 + quad * 8);
            acc = __builtin_amdgcn_mfma_f32_16x16x32_bf16(af, bf[ks], acc, 0, 0, 0);
        }
        #pragma unroll
        for (int r = 0; r < 4; ++r) {
            int o = ot * 16 + quad * 4 + r;
            size_t oi = ((size_t)b * CC_ + o) * LL_ + l0 + n;
            out[oi] = acc[r] + bo[o] + x[oi];
        }
    }
}

extern "C" void kernel_launch(void* const* d_in, const int* in_sizes, int n_in,
                              void* d_out, int out_size, void* d_ws, size_t ws_size,
                              hipStream_t stream) {
    const float* x  = (const float*)d_in[0];
    const float* g  = (const float*)d_in[1];
    const float* bv = (const float*)d_in[2];
    const float* Wq = (const float*)d_in[3];
    const float* Wk = (const float*)d_in[4];
    const float* Wv = (const float*)d_in[5];
    const float* Wo = (const float*)d_in[6];
    const float* bo = (const float*)d_in[7];
    float* out = (float*)d_out;

    const size_t qkv_elems = (size_t)BB_ * HEADS_ * LL_ * DHEAD_;
    short* q    = (short*)d_ws;
    short* k    = q + qkv_elems;
    short* v    = k + qkv_elems;
    short* ao   = v + qkv_elems;
    short* wqkv = ao + qkv_elems;
    short* wo   = wqkv + 384 * 256;
    float2* gb  = (float2*)(wo + 256 * 128);

    k_prep  <<<dim3(512), dim3(256), 0, stream>>>(Wq, Wk, Wv, Wo, g, bv, wqkv, wo, gb);
    k_ln_qkv<<<dim3(LL_ / 32, BB_), dim3(512), 0, stream>>>(x, wqkv, gb, q, k, v);
    k_attn  <<<dim3(LL_ / 128, BB_ * HEADS_), dim3(256), 0, stream>>>(q, k, v, ao);
    k_oproj <<<dim3(LL_ / 16, 2, BB_), dim3(256), 0, stream>>>(ao, wo, bo, x, out);
}

// Round 14
// 163.240 us; speedup vs baseline: 1.1386x; 1.0211x over previous
//
#include <hip/hip_runtime.h>
#include <math.h>

#define BB_ 8
#define CC_ 256
#define LL_ 2048
#define HEADS_ 4
#define DHEAD_ 32
#define HID_ 128
#define EPS_ 1e-5f
#define SCALE_ 0.17677669529663687f   // 32^-0.5
#define K1_ (SCALE_ * 1.44269504088896f)   // folded into Wq at prep time

typedef short v8s  __attribute__((ext_vector_type(8)));
typedef float v4f  __attribute__((ext_vector_type(4)));
typedef float v16f __attribute__((ext_vector_type(16)));
typedef unsigned v4u __attribute__((ext_vector_type(4)));

__device__ inline short f2bf(float x) {   // RNE f32 -> bf16 bits
    union { float f; unsigned u; } a; a.f = x;
    unsigned r = a.u + 0x7fffu + ((a.u >> 16) & 1u);
    return (short)(r >> 16);
}
__device__ inline unsigned fbits(float x) { union { float f; unsigned u; } a; a.f = x; return a.u; }

// ---------------------------------------------------------------------------
// Kernel 0: weight prep (shfl-reduce, 1 barrier). W' = W*g (q *K1) -> bf16;
// gamma[o]=sum(W'), beta[o]=sum(W*b) -> gb[o]. Blocks 384..511: Wo -> bf16.
// ---------------------------------------------------------------------------
__global__ __launch_bounds__(256) void k_prep(
    const float* __restrict__ Wq, const float* __restrict__ Wk, const float* __restrict__ Wv,
    const float* __restrict__ Wo, const float* __restrict__ g, const float* __restrict__ bvec,
    short* __restrict__ wqkv, short* __restrict__ wo, float2* __restrict__ gb)
{
    __shared__ float red0[4], red1[4];
    const int blk = blockIdx.x, c = threadIdx.x;
    const int wave = c >> 6, lane = c & 63;
    if (blk < 384) {
        const float* W; int oo; float scale = 1.f;
        if (blk < 128)      { W = Wq; oo = blk;       scale = K1_; }
        else if (blk < 256) { W = Wk; oo = blk - 128; }
        else                { W = Wv; oo = blk - 256; }
        float w  = W[oo * 256 + c] * scale;
        float wg = w * g[c];
        wqkv[blk * 256 + c] = f2bf(wg);
        float r0 = wg, r1 = w * bvec[c];
        #pragma unroll
        for (int off = 1; off < 64; off <<= 1) {
            r0 += __shfl_xor(r0, off, 64);
            r1 += __shfl_xor(r1, off, 64);
        }
        if (lane == 0) { red0[wave] = r0; red1[wave] = r1; }
        __syncthreads();
        if (c == 0)
            gb[blk] = make_float2(red0[0] + red0[1] + red0[2] + red0[3],
                                  red1[0] + red1[1] + red1[2] + red1[3]);
    } else {
        int i2 = (blk - 384) * 256 + c;
        wo[i2] = f2bf(Wo[i2]);
    }
}

// ---------------------------------------------------------------------------
// Kernel 1: LayerNorm-folded QKV projection, slimmed: x staged DIRECTLY as
// bf16 into xnT (LN folded into weights; stats only needed in epilogue),
// stats partials in registers -> ps_; epilogue reduces its own 4 rows via
// broadcast LDS reads. 3 barriers (was 5), 31 KB LDS (was 71).
// q,k: [B*H, L, 32]; v: [B*H, 32, L] bf16.
// ---------------------------------------------------------------------------
__global__ __launch_bounds__(512) void k_ln_qkv(
    const float* __restrict__ x, const short* __restrict__ wqkv, const float2* __restrict__ gb,
    short* __restrict__ q, short* __restrict__ k, short* __restrict__ v)
{
    __shared__ short xnT[32 * 264];      // raw bf16 [l][c], later reused as q|k staging
    __shared__ short st2[128 * 48];      // v staging: [o'][l]
    __shared__ float ps_[8 * 32], ps2_[8 * 32];
    const int b   = blockIdx.y;
    const int l0  = blockIdx.x * 32;
    const int tid = threadIdx.x;
    const int wave = tid >> 6, lane = tid & 63;

    // stage x -> bf16 xnT (transpose) + stats partials in registers
    {
        const int ls = tid & 31;
        const int cg = tid >> 5;          // 0..15
        float s = 0.f, s2 = 0.f;
        #pragma unroll
        for (int kk = 0; kk < 8; ++kk) {
            int c = 2 * cg + 32 * kk;
            float t0 = x[((size_t)b * CC_ + c) * LL_ + l0 + ls];
            float t1 = x[((size_t)b * CC_ + c + 1) * LL_ + l0 + ls];
            s += t0 + t1; s2 += t0 * t0 + t1 * t1;
            unsigned pk = (unsigned short)f2bf(t0) | ((unsigned)(unsigned short)f2bf(t1) << 16);
            *(unsigned*)(xnT + ls * 264 + c) = pk;
        }
        s  += __shfl_xor(s, 32, 64);      // combine the wave's two c-columns
        s2 += __shfl_xor(s2, 32, 64);
        if (lane < 32) { ps_[wave * 32 + lane] = s; ps2_[wave * 32 + lane] = s2; }
    }
    __syncthreads();

    const int n = lane & 15, quad = lane >> 4;
    const int rowbase = (wave >> 2) * 16;
    const int colbase = (wave & 3) * 96;

    v4f acc[6];
    #pragma unroll
    for (int ct = 0; ct < 6; ++ct) acc[ct] = (v4f){0.f, 0.f, 0.f, 0.f};

    #pragma unroll
    for (int ks = 0; ks < 8; ++ks) {
        const v8s af = *(const v8s*)(xnT + (rowbase + n) * 264 + ks * 32 + quad * 8);
        #pragma unroll
        for (int ct = 0; ct < 6; ++ct) {
            const v8s bfrag = *(const v8s*)(wqkv + (size_t)(colbase + ct * 16 + n) * 256 + ks * 32 + quad * 8);
            acc[ct] = __builtin_amdgcn_mfma_f32_16x16x32_bf16(af, bfrag, acc[ct], 0, 0, 0);
        }
    }
    __syncthreads();   // all waves done reading xnT; safe to reuse as staging

    // per-lane stats for its 4 rows (broadcast LDS reads: 16 lanes same addr)
    float rsv[4], rmv[4];
    #pragma unroll
    for (int r = 0; r < 4; ++r) {
        int l = rowbase + quad * 4 + r;
        float s = 0.f, s2 = 0.f;
        #pragma unroll
        for (int p = 0; p < 8; ++p) { s += ps_[p * 32 + l]; s2 += ps2_[p * 32 + l]; }
        float mean = s * (1.f / CC_);
        float var  = s2 * (1.f / CC_) - mean * mean;
        float rs   = rsqrtf(var + EPS_);
        rsv[r] = rs; rmv[r] = rs * mean;
    }
    #pragma unroll
    for (int ct = 0; ct < 6; ++ct) {
        int o = colbase + ct * 16 + n;
        float2 gbo = gb[o];
        #pragma unroll
        for (int r = 0; r < 4; ++r) {
            int l = rowbase + quad * 4 + r;
            float val = rsv[r] * acc[ct][r] - rmv[r] * gbo.x + gbo.y;
            if (o < 256)      xnT[l * 264 + o] = f2bf(val);
            else              st2[(o - 256) * 48 + l] = f2bf(val);
        }
    }
    __syncthreads();

    {
        int u = tid;
        int h = u >> 7, rest = u & 127;
        int l = rest >> 2, dg = rest & 3;
        size_t bh = (size_t)b * HEADS_ + h;
        v8s qv = *(const v8s*)(xnT + l * 264 + h * 32 + dg * 8);
        *(v8s*)(q + (bh * LL_ + l0 + l) * DHEAD_ + dg * 8) = qv;
        v8s kv = *(const v8s*)(xnT + l * 264 + 128 + h * 32 + dg * 8);
        *(v8s*)(k + (bh * LL_ + l0 + l) * DHEAD_ + dg * 8) = kv;

        int op = u >> 2, lg = u & 3;
        v8s vv = *(const v8s*)(st2 + op * 48 + lg * 8);
        int h2 = op >> 5, d = op & 31;
        *(v8s*)(v + (((size_t)b * HEADS_ + h2) * DHEAD_ + d) * LL_ + l0 + lg * 8) = vv;
    }
}

// ---------------------------------------------------------------------------
// Kernel 2: flash attention (unchanged r13: block-shared K/V via LDS,
// 4 q-waves x 32 q over all 2048 keys, no split-K).
// ---------------------------------------------------------------------------
#define CHK_ 256                         // keys per staged chunk
__global__ __launch_bounds__(256) void k_attn(
    const short* __restrict__ q, const short* __restrict__ k, const short* __restrict__ v,
    short* __restrict__ ao)
{
    __shared__ short Kb[CHK_ * 40];      // [key][d pad40]
    __shared__ short Vb[32 * 264];       // [d][key pad264]
    const int bh   = blockIdx.y;
    const int b    = bh >> 2, h = bh & 3;
    const int tid  = threadIdx.x;
    const int wave = tid >> 6, lane = tid & 63;
    const int m    = lane & 31;
    const int half = lane >> 5;
    const size_t kvbase = (size_t)bh * LL_ * DHEAD_;
    const size_t vbase  = (size_t)bh * DHEAD_ * LL_;

    const int q0 = blockIdx.x * 128 + wave * 32;

    const v8s qf0 = *(const v8s*)(q + kvbase + (size_t)(q0 + m) * DHEAD_ + half * 8);
    const v8s qf1 = *(const v8s*)(q + kvbase + (size_t)(q0 + m) * DHEAD_ + 16 + half * 8);

    v16f O = {};
    float psum = 0.f;

    for (int kc = 0; kc < LL_; kc += CHK_) {
        __syncthreads();
        {
            const short* src = k + kvbase + (size_t)(kc + tid) * DHEAD_;
            short* dst = Kb + tid * 40;
            #pragma unroll
            for (int j = 0; j < 4; ++j)
                *(v8s*)(dst + j * 8) = *(const v8s*)(src + j * 8);
        }
        {
            const int col = (tid & 31) * 8, dr = tid >> 5;
            #pragma unroll
            for (int p = 0; p < 4; ++p) {
                int d = p * 8 + dr;
                *(v8s*)(Vb + d * 264 + col) =
                    *(const v8s*)(v + vbase + (size_t)d * LL_ + kc + col);
            }
        }
        __syncthreads();

        #pragma unroll
        for (int ktl = 0; ktl < CHK_; ktl += 32) {
            const v8s kf0 = *(const v8s*)(Kb + (ktl + m) * 40 + half * 8);
            const v8s kf1 = *(const v8s*)(Kb + (ktl + m) * 40 + 16 + half * 8);
            v16f S = __builtin_amdgcn_mfma_f32_32x32x16_bf16(kf0, qf0, (v16f){}, 0, 0, 0);
            S      = __builtin_amdgcn_mfma_f32_32x32x16_bf16(kf1, qf1, S,        0, 0, 0);

            const v8s vf0 = *(const v8s*)(Vb + m * 264 + ktl + half * 8);
            const v8s vf1 = *(const v8s*)(Vb + m * 264 + ktl + 16 + half * 8);

            unsigned e[8];
            #pragma unroll
            for (int i = 0; i < 8; ++i) {
                float pa = __builtin_amdgcn_exp2f(S[2 * i]);
                float pb = __builtin_amdgcn_exp2f(S[2 * i + 1]);
                psum += pa + pb;
                e[i] = __builtin_amdgcn_perm(fbits(pb) + 0x8000u, fbits(pa) + 0x8000u, 0x07060302u);
            }
            v4u f1, f2;
#if __has_builtin(__builtin_amdgcn_permlane32_swap)
            {
                auto r02 = __builtin_amdgcn_permlane32_swap(e[0], e[2], false, false);
                auto r13 = __builtin_amdgcn_permlane32_swap(e[1], e[3], false, false);
                auto r46 = __builtin_amdgcn_permlane32_swap(e[4], e[6], false, false);
                auto r57 = __builtin_amdgcn_permlane32_swap(e[5], e[7], false, false);
                f1 = (v4u){r02[0], r13[0], r02[1], r13[1]};
                f2 = (v4u){r46[0], r57[0], r46[1], r57[1]};
            }
#else
            {
                unsigned o0 = __shfl_xor(e[0], 32, 64), o1 = __shfl_xor(e[1], 32, 64);
                unsigned o2 = __shfl_xor(e[2], 32, 64), o3 = __shfl_xor(e[3], 32, 64);
                unsigned o4 = __shfl_xor(e[4], 32, 64), o5 = __shfl_xor(e[5], 32, 64);
                unsigned o6 = __shfl_xor(e[6], 32, 64), o7 = __shfl_xor(e[7], 32, 64);
                f1 = half ? (v4u){o2, o3, e[2], e[3]} : (v4u){e[0], e[1], o0, o1};
                f2 = half ? (v4u){o6, o7, e[6], e[7]} : (v4u){e[4], e[5], o4, o5};
            }
#endif
            O = __builtin_amdgcn_mfma_f32_32x32x16_bf16(__builtin_bit_cast(v8s, f1), vf0, O, 0, 0, 0);
            O = __builtin_amdgcn_mfma_f32_32x32x16_bf16(__builtin_bit_cast(v8s, f2), vf1, O, 0, 0, 0);
        }
    }

    psum += __shfl_xor(psum, 32, 64);
    float invden = 1.f / psum;
    #pragma unroll
    for (int r = 0; r < 16; ++r) {
        int qr = (r & 3) + 8 * (r >> 2) + 4 * half;
        float inv = __shfl(invden, qr, 64);
        int row = q0 + qr;
        ao[((size_t)b * LL_ + row) * HID_ + h * DHEAD_ + m] = f2bf(O[r] * inv);
    }
}

// ---------------------------------------------------------------------------
// Kernel 3: output projection, 32x32 MFMA with l on D-columns: out/x
// accessed in fully-coalesced 128B rows. A=wo (global, L1-hot), B=ao rows.
// Block 256 thr = 4 waves x 32-o tile; grid (L/32, o-half, B) = 1024 blocks.
// ---------------------------------------------------------------------------
__global__ __launch_bounds__(256) void k_oproj(
    const short* __restrict__ ao, const short* __restrict__ wo, const float* __restrict__ bo,
    const float* __restrict__ x, float* __restrict__ out)
{
    const int b = blockIdx.z;
    const int l0 = blockIdx.x * 32;
    const int tid = threadIdx.x;
    const int wave = tid >> 6, lane = tid & 63;
    const int m = lane & 31, half = lane >> 5;
    const int o0 = blockIdx.y * 128 + wave * 32;

    // B-frags: B[k][n=l] -> lane n holds ao[l0+n][k], contiguous 16B each
    v8s bf[8];
    #pragma unroll
    for (int ks = 0; ks < 8; ++ks)
        bf[ks] = *(const v8s*)(ao + ((size_t)b * LL_ + l0 + m) * HID_ + ks * 16 + half * 8);

    v16f acc = {};
    #pragma unroll
    for (int ks = 0; ks < 8; ++ks) {
        const v8s af = *(const v8s*)(wo + (size_t)(o0 + m) * HID_ + ks * 16 + half * 8);
        acc = __builtin_amdgcn_mfma_f32_32x32x16_bf16(af, bf[ks], acc, 0, 0, 0);
    }

    // D: col = lane&31 = l (coalesced 128B stores), row r -> o
    #pragma unroll
    for (int r = 0; r < 16; ++r) {
        int o = o0 + (r & 3) + 8 * (r >> 2) + 4 * half;
        size_t oi = ((size_t)b * CC_ + o) * LL_ + l0 + m;
        out[oi] = acc[r] + bo[o] + x[oi];
    }
}

extern "C" void kernel_launch(void* const* d_in, const int* in_sizes, int n_in,
                              void* d_out, int out_size, void* d_ws, size_t ws_size,
                              hipStream_t stream) {
    const float* x  = (const float*)d_in[0];
    const float* g  = (const float*)d_in[1];
    const float* bv = (const float*)d_in[2];
    const float* Wq = (const float*)d_in[3];
    const float* Wk = (const float*)d_in[4];
    const float* Wv = (const float*)d_in[5];
    const float* Wo = (const float*)d_in[6];
    const float* bo = (const float*)d_in[7];
    float* out = (float*)d_out;

    const size_t qkv_elems = (size_t)BB_ * HEADS_ * LL_ * DHEAD_;
    short* q    = (short*)d_ws;
    short* k    = q + qkv_elems;
    short* v    = k + qkv_elems;
    short* ao   = v + qkv_elems;
    short* wqkv = ao + qkv_elems;
    short* wo   = wqkv + 384 * 256;
    float2* gb  = (float2*)(wo + 256 * 128);

    k_prep  <<<dim3(512), dim3(256), 0, stream>>>(Wq, Wk, Wv, Wo, g, bv, wqkv, wo, gb);
    k_ln_qkv<<<dim3(LL_ / 32, BB_), dim3(512), 0, stream>>>(x, wqkv, gb, q, k, v);
    k_attn  <<<dim3(LL_ / 128, BB_ * HEADS_), dim3(256), 0, stream>>>(q, k, v, ao);
    k_oproj <<<dim3(LL_ / 32, 2, BB_), dim3(256), 0, stream>>>(ao, wo, bo, x, out);
}

// Round 15
// 157.251 us; speedup vs baseline: 1.1820x; 1.0381x over previous
//
#include <hip/hip_runtime.h>
#include <math.h>

#define BB_ 8
#define CC_ 256
#define LL_ 2048
#define HEADS_ 4
#define DHEAD_ 32
#define HID_ 128
#define EPS_ 1e-5f
#define SCALE_ 0.17677669529663687f   // 32^-0.5
#define K1_ (SCALE_ * 1.44269504088896f)   // folded into Wq at prep time

typedef short v8s  __attribute__((ext_vector_type(8)));
typedef float v4f  __attribute__((ext_vector_type(4)));
typedef float v16f __attribute__((ext_vector_type(16)));
typedef unsigned v4u __attribute__((ext_vector_type(4)));

__device__ inline short f2bf(float x) {   // RNE f32 -> bf16 bits
    union { float f; unsigned u; } a; a.f = x;
    unsigned r = a.u + 0x7fffu + ((a.u >> 16) & 1u);
    return (short)(r >> 16);
}
__device__ inline unsigned fbits(float x) { union { float f; unsigned u; } a; a.f = x; return a.u; }

// ---------------------------------------------------------------------------
// Kernel 0: weight prep (unchanged r14).
// ---------------------------------------------------------------------------
__global__ __launch_bounds__(256) void k_prep(
    const float* __restrict__ Wq, const float* __restrict__ Wk, const float* __restrict__ Wv,
    const float* __restrict__ Wo, const float* __restrict__ g, const float* __restrict__ bvec,
    short* __restrict__ wqkv, short* __restrict__ wo, float2* __restrict__ gb)
{
    __shared__ float red0[4], red1[4];
    const int blk = blockIdx.x, c = threadIdx.x;
    const int wave = c >> 6, lane = c & 63;
    if (blk < 384) {
        const float* W; int oo; float scale = 1.f;
        if (blk < 128)      { W = Wq; oo = blk;       scale = K1_; }
        else if (blk < 256) { W = Wk; oo = blk - 128; }
        else                { W = Wv; oo = blk - 256; }
        float w  = W[oo * 256 + c] * scale;
        float wg = w * g[c];
        wqkv[blk * 256 + c] = f2bf(wg);
        float r0 = wg, r1 = w * bvec[c];
        #pragma unroll
        for (int off = 1; off < 64; off <<= 1) {
            r0 += __shfl_xor(r0, off, 64);
            r1 += __shfl_xor(r1, off, 64);
        }
        if (lane == 0) { red0[wave] = r0; red1[wave] = r1; }
        __syncthreads();
        if (c == 0)
            gb[blk] = make_float2(red0[0] + red0[1] + red0[2] + red0[3],
                                  red1[0] + red1[1] + red1[2] + red1[3]);
    } else {
        int i2 = (blk - 384) * 256 + c;
        wo[i2] = f2bf(Wo[i2]);
    }
}

// ---------------------------------------------------------------------------
// Kernel 1: LayerNorm-folded QKV projection (unchanged r14).
// ---------------------------------------------------------------------------
__global__ __launch_bounds__(512) void k_ln_qkv(
    const float* __restrict__ x, const short* __restrict__ wqkv, const float2* __restrict__ gb,
    short* __restrict__ q, short* __restrict__ k, short* __restrict__ v)
{
    __shared__ short xnT[32 * 264];
    __shared__ short st2[128 * 48];
    __shared__ float ps_[8 * 32], ps2_[8 * 32];
    const int b   = blockIdx.y;
    const int l0  = blockIdx.x * 32;
    const int tid = threadIdx.x;
    const int wave = tid >> 6, lane = tid & 63;

    {
        const int ls = tid & 31;
        const int cg = tid >> 5;
        float s = 0.f, s2 = 0.f;
        #pragma unroll
        for (int kk = 0; kk < 8; ++kk) {
            int c = 2 * cg + 32 * kk;
            float t0 = x[((size_t)b * CC_ + c) * LL_ + l0 + ls];
            float t1 = x[((size_t)b * CC_ + c + 1) * LL_ + l0 + ls];
            s += t0 + t1; s2 += t0 * t0 + t1 * t1;
            unsigned pk = (unsigned short)f2bf(t0) | ((unsigned)(unsigned short)f2bf(t1) << 16);
            *(unsigned*)(xnT + ls * 264 + c) = pk;
        }
        s  += __shfl_xor(s, 32, 64);
        s2 += __shfl_xor(s2, 32, 64);
        if (lane < 32) { ps_[wave * 32 + lane] = s; ps2_[wave * 32 + lane] = s2; }
    }
    __syncthreads();

    const int n = lane & 15, quad = lane >> 4;
    const int rowbase = (wave >> 2) * 16;
    const int colbase = (wave & 3) * 96;

    v4f acc[6];
    #pragma unroll
    for (int ct = 0; ct < 6; ++ct) acc[ct] = (v4f){0.f, 0.f, 0.f, 0.f};

    #pragma unroll
    for (int ks = 0; ks < 8; ++ks) {
        const v8s af = *(const v8s*)(xnT + (rowbase + n) * 264 + ks * 32 + quad * 8);
        #pragma unroll
        for (int ct = 0; ct < 6; ++ct) {
            const v8s bfrag = *(const v8s*)(wqkv + (size_t)(colbase + ct * 16 + n) * 256 + ks * 32 + quad * 8);
            acc[ct] = __builtin_amdgcn_mfma_f32_16x16x32_bf16(af, bfrag, acc[ct], 0, 0, 0);
        }
    }
    __syncthreads();

    float rsv[4], rmv[4];
    #pragma unroll
    for (int r = 0; r < 4; ++r) {
        int l = rowbase + quad * 4 + r;
        float s = 0.f, s2 = 0.f;
        #pragma unroll
        for (int p = 0; p < 8; ++p) { s += ps_[p * 32 + l]; s2 += ps2_[p * 32 + l]; }
        float mean = s * (1.f / CC_);
        float var  = s2 * (1.f / CC_) - mean * mean;
        float rs   = rsqrtf(var + EPS_);
        rsv[r] = rs; rmv[r] = rs * mean;
    }
    #pragma unroll
    for (int ct = 0; ct < 6; ++ct) {
        int o = colbase + ct * 16 + n;
        float2 gbo = gb[o];
        #pragma unroll
        for (int r = 0; r < 4; ++r) {
            int l = rowbase + quad * 4 + r;
            float val = rsv[r] * acc[ct][r] - rmv[r] * gbo.x + gbo.y;
            if (o < 256)      xnT[l * 264 + o] = f2bf(val);
            else              st2[(o - 256) * 48 + l] = f2bf(val);
        }
    }
    __syncthreads();

    {
        int u = tid;
        int h = u >> 7, rest = u & 127;
        int l = rest >> 2, dg = rest & 3;
        size_t bh = (size_t)b * HEADS_ + h;
        v8s qv = *(const v8s*)(xnT + l * 264 + h * 32 + dg * 8);
        *(v8s*)(q + (bh * LL_ + l0 + l) * DHEAD_ + dg * 8) = qv;
        v8s kv = *(const v8s*)(xnT + l * 264 + 128 + h * 32 + dg * 8);
        *(v8s*)(k + (bh * LL_ + l0 + l) * DHEAD_ + dg * 8) = kv;

        int op = u >> 2, lg = u & 3;
        v8s vv = *(const v8s*)(st2 + op * 48 + lg * 8);
        int h2 = op >> 5, d = op & 31;
        *(v8s*)(v + (((size_t)b * HEADS_ + h2) * DHEAD_ + d) * LL_ + l0 + lg * 8) = vv;
    }
}

// ---------------------------------------------------------------------------
// Kernel 2: flash attention, 32x32x16 MFMA, S^T, no max-subtraction.
// r13 LDS-shared K/V + 2-way split-K: 512 thr = 4 q-waves x 2 key-halves.
// Per 128-key chunk both halves staged cooperatively (Kb[2], Vb[2]); waves
// read only LDS. Grid 512 blocks -> 16 waves/CU (2x r14 residency).
// Ost (split-K combine) aliases Kb with barriers on both sides.
// ---------------------------------------------------------------------------
__global__ __launch_bounds__(512) void k_attn(
    const short* __restrict__ q, const short* __restrict__ k, const short* __restrict__ v,
    short* __restrict__ ao)
{
    __shared__ char smem[20480 + 17408 + 512];
    short* Kb     = (short*)smem;                      // [2][128*40]  (hh*5120)
    short* Vb     = (short*)(smem + 20480);            // [2][32*136]  (hh*4352)
    float* Ost    = (float*)smem;                      // alias Kb: [4][32][32]
    float* psumst = (float*)(smem + 20480 + 17408);    // [4*32]

    const int bh   = blockIdx.y;
    const int b    = bh >> 2, h = bh & 3;
    const int tid  = threadIdx.x;
    const int wave = tid >> 6, lane = tid & 63;
    const int wq   = wave & 3;           // q-subtile
    const int kh   = wave >> 2;          // key half: [kh*1024, +1024)
    const int m    = lane & 31;
    const int half = lane >> 5;
    const size_t kvbase = (size_t)bh * LL_ * DHEAD_;   // q,k: [bh][l][32]
    const size_t vbase  = (size_t)bh * DHEAD_ * LL_;   // v:   [bh][d][L]

    const int q0 = blockIdx.x * 128 + wq * 32;

    const v8s qf0 = *(const v8s*)(q + kvbase + (size_t)(q0 + m) * DHEAD_ + half * 8);
    const v8s qf1 = *(const v8s*)(q + kvbase + (size_t)(q0 + m) * DHEAD_ + 16 + half * 8);

    v16f O = {};
    float psum = 0.f;

    // staging coords (whole block stages both halves each chunk)
    const int s_hh  = (tid >> 7) & 1;     // which key-half for K staging
    const int s_r   = tid & 127;          // key row
    const int s_p   = tid >> 8;           // 16-half part (0/1)
    const int v_hh  = tid >> 8;           // which key-half for V staging
    const int v_d   = (tid >> 3) & 31;    // d row
    const int v_cg  = tid & 7;            // 16-half col group

    for (int kc = 0; kc < 1024; kc += 128) {
        __syncthreads();   // previous chunk's readers done
        {   // K: 2 halves x 128 rows x 32 halves
            const short* src = k + kvbase + (size_t)(s_hh * 1024 + kc + s_r) * DHEAD_ + s_p * 16;
            short* dst = Kb + s_hh * 5120 + s_r * 40 + s_p * 16;
            *(v8s*)dst       = *(const v8s*)src;
            *(v8s*)(dst + 8) = *(const v8s*)(src + 8);
        }
        {   // V: 2 halves x 32 d-rows x 128 cols
            const short* src = v + vbase + (size_t)v_d * LL_ + v_hh * 1024 + kc + v_cg * 16;
            short* dst = Vb + v_hh * 4352 + v_d * 136 + v_cg * 16;
            *(v8s*)dst       = *(const v8s*)src;
            *(v8s*)(dst + 8) = *(const v8s*)(src + 8);
        }
        __syncthreads();

        const short* Kw = Kb + kh * 5120;
        const short* Vw = Vb + kh * 4352;
        #pragma unroll
        for (int ktl = 0; ktl < 128; ktl += 32) {
            const v8s kf0 = *(const v8s*)(Kw + (ktl + m) * 40 + half * 8);
            const v8s kf1 = *(const v8s*)(Kw + (ktl + m) * 40 + 16 + half * 8);
            v16f S = __builtin_amdgcn_mfma_f32_32x32x16_bf16(kf0, qf0, (v16f){}, 0, 0, 0);
            S      = __builtin_amdgcn_mfma_f32_32x32x16_bf16(kf1, qf1, S,        0, 0, 0);

            const v8s vf0 = *(const v8s*)(Vw + m * 136 + ktl + half * 8);
            const v8s vf1 = *(const v8s*)(Vw + m * 136 + ktl + 16 + half * 8);

            unsigned e[8];
            #pragma unroll
            for (int i = 0; i < 8; ++i) {
                float pa = __builtin_amdgcn_exp2f(S[2 * i]);
                float pb = __builtin_amdgcn_exp2f(S[2 * i + 1]);
                psum += pa + pb;
                e[i] = __builtin_amdgcn_perm(fbits(pb) + 0x8000u, fbits(pa) + 0x8000u, 0x07060302u);
            }
            v4u f1, f2;
#if __has_builtin(__builtin_amdgcn_permlane32_swap)
            {
                auto r02 = __builtin_amdgcn_permlane32_swap(e[0], e[2], false, false);
                auto r13 = __builtin_amdgcn_permlane32_swap(e[1], e[3], false, false);
                auto r46 = __builtin_amdgcn_permlane32_swap(e[4], e[6], false, false);
                auto r57 = __builtin_amdgcn_permlane32_swap(e[5], e[7], false, false);
                f1 = (v4u){r02[0], r13[0], r02[1], r13[1]};
                f2 = (v4u){r46[0], r57[0], r46[1], r57[1]};
            }
#else
            {
                unsigned o0 = __shfl_xor(e[0], 32, 64), o1 = __shfl_xor(e[1], 32, 64);
                unsigned o2 = __shfl_xor(e[2], 32, 64), o3 = __shfl_xor(e[3], 32, 64);
                unsigned o4 = __shfl_xor(e[4], 32, 64), o5 = __shfl_xor(e[5], 32, 64);
                unsigned o6 = __shfl_xor(e[6], 32, 64), o7 = __shfl_xor(e[7], 32, 64);
                f1 = half ? (v4u){o2, o3, e[2], e[3]} : (v4u){e[0], e[1], o0, o1};
                f2 = half ? (v4u){o6, o7, e[6], e[7]} : (v4u){e[4], e[5], o4, o5};
            }
#endif
            O = __builtin_amdgcn_mfma_f32_32x32x16_bf16(__builtin_bit_cast(v8s, f1), vf0, O, 0, 0, 0);
            O = __builtin_amdgcn_mfma_f32_32x32x16_bf16(__builtin_bit_cast(v8s, f2), vf1, O, 0, 0, 0);
        }
    }

    psum += __shfl_xor(psum, 32, 64);    // lane m: den-partial for q = m

    __syncthreads();   // all waves done reading Kb before Ost (alias) writes
    if (kh == 1) {
        #pragma unroll
        for (int r = 0; r < 16; ++r) {
            int qr = (r & 3) + 8 * (r >> 2) + 4 * half;
            Ost[(wq * 32 + qr) * 32 + m] = O[r];
        }
        if (half == 0) psumst[wq * 32 + m] = psum;
    }
    __syncthreads();
    if (kh == 0) {
        float den = psum + psumst[wq * 32 + m];
        float invden = 1.f / den;
        #pragma unroll
        for (int r = 0; r < 16; ++r) {
            int qr = (r & 3) + 8 * (r >> 2) + 4 * half;
            float inv = __shfl(invden, qr, 64);
            float val = (O[r] + Ost[(wq * 32 + qr) * 32 + m]) * inv;
            int row = q0 + qr;
            ao[((size_t)b * LL_ + row) * HID_ + h * DHEAD_ + m] = f2bf(val);
        }
    }
}

// ---------------------------------------------------------------------------
// Kernel 3: output projection (unchanged r14: 32x32 MFMA, l on D-columns).
// ---------------------------------------------------------------------------
__global__ __launch_bounds__(256) void k_oproj(
    const short* __restrict__ ao, const short* __restrict__ wo, const float* __restrict__ bo,
    const float* __restrict__ x, float* __restrict__ out)
{
    const int b = blockIdx.z;
    const int l0 = blockIdx.x * 32;
    const int tid = threadIdx.x;
    const int wave = tid >> 6, lane = tid & 63;
    const int m = lane & 31, half = lane >> 5;
    const int o0 = blockIdx.y * 128 + wave * 32;

    v8s bf[8];
    #pragma unroll
    for (int ks = 0; ks < 8; ++ks)
        bf[ks] = *(const v8s*)(ao + ((size_t)b * LL_ + l0 + m) * HID_ + ks * 16 + half * 8);

    v16f acc = {};
    #pragma unroll
    for (int ks = 0; ks < 8; ++ks) {
        const v8s af = *(const v8s*)(wo + (size_t)(o0 + m) * HID_ + ks * 16 + half * 8);
        acc = __builtin_amdgcn_mfma_f32_32x32x16_bf16(af, bf[ks], acc, 0, 0, 0);
    }

    #pragma unroll
    for (int r = 0; r < 16; ++r) {
        int o = o0 + (r & 3) + 8 * (r >> 2) + 4 * half;
        size_t oi = ((size_t)b * CC_ + o) * LL_ + l0 + m;
        out[oi] = acc[r] + bo[o] + x[oi];
    }
}

extern "C" void kernel_launch(void* const* d_in, const int* in_sizes, int n_in,
                              void* d_out, int out_size, void* d_ws, size_t ws_size,
                              hipStream_t stream) {
    const float* x  = (const float*)d_in[0];
    const float* g  = (const float*)d_in[1];
    const float* bv = (const float*)d_in[2];
    const float* Wq = (const float*)d_in[3];
    const float* Wk = (const float*)d_in[4];
    const float* Wv = (const float*)d_in[5];
    const float* Wo = (const float*)d_in[6];
    const float* bo = (const float*)d_in[7];
    float* out = (float*)d_out;

    const size_t qkv_elems = (size_t)BB_ * HEADS_ * LL_ * DHEAD_;
    short* q    = (short*)d_ws;
    short* k    = q + qkv_elems;
    short* v    = k + qkv_elems;
    short* ao   = v + qkv_elems;
    short* wqkv = ao + qkv_elems;
    short* wo   = wqkv + 384 * 256;
    float2* gb  = (float2*)(wo + 256 * 128);

    k_prep  <<<dim3(512), dim3(256), 0, stream>>>(Wq, Wk, Wv, Wo, g, bv, wqkv, wo, gb);
    k_ln_qkv<<<dim3(LL_ / 32, BB_), dim3(512), 0, stream>>>(x, wqkv, gb, q, k, v);
    k_attn  <<<dim3(LL_ / 128, BB_ * HEADS_), dim3(512), 0, stream>>>(q, k, v, ao);
    k_oproj <<<dim3(LL_ / 32, 2, BB_), dim3(256), 0, stream>>>(ao, wo, bo, x, out);
}

// Round 16
// 148.510 us; speedup vs baseline: 1.2515x; 1.0589x over previous
//
#include <hip/hip_runtime.h>
#include <math.h>

#define BB_ 8
#define CC_ 256
#define LL_ 2048
#define HEADS_ 4
#define DHEAD_ 32
#define HID_ 128
#define EPS_ 1e-5f
#define SCALE_ 0.17677669529663687f   // 32^-0.5
#define K1_ (SCALE_ * 1.44269504088896f)   // folded into Wq at prep time

typedef short v8s  __attribute__((ext_vector_type(8)));
typedef float v4f  __attribute__((ext_vector_type(4)));
typedef float v16f __attribute__((ext_vector_type(16)));
typedef unsigned v4u __attribute__((ext_vector_type(4)));

__device__ inline short f2bf(float x) {   // RNE f32 -> bf16 bits
    union { float f; unsigned u; } a; a.f = x;
    unsigned r = a.u + 0x7fffu + ((a.u >> 16) & 1u);
    return (short)(r >> 16);
}
__device__ inline unsigned fbits(float x) { union { float f; unsigned u; } a; a.f = x; return a.u; }

// ---------------------------------------------------------------------------
// Kernel 0: weight prep (unchanged r15).
// ---------------------------------------------------------------------------
__global__ __launch_bounds__(256) void k_prep(
    const float* __restrict__ Wq, const float* __restrict__ Wk, const float* __restrict__ Wv,
    const float* __restrict__ Wo, const float* __restrict__ g, const float* __restrict__ bvec,
    short* __restrict__ wqkv, short* __restrict__ wo, float2* __restrict__ gb)
{
    __shared__ float red0[4], red1[4];
    const int blk = blockIdx.x, c = threadIdx.x;
    const int wave = c >> 6, lane = c & 63;
    if (blk < 384) {
        const float* W; int oo; float scale = 1.f;
        if (blk < 128)      { W = Wq; oo = blk;       scale = K1_; }
        else if (blk < 256) { W = Wk; oo = blk - 128; }
        else                { W = Wv; oo = blk - 256; }
        float w  = W[oo * 256 + c] * scale;
        float wg = w * g[c];
        wqkv[blk * 256 + c] = f2bf(wg);
        float r0 = wg, r1 = w * bvec[c];
        #pragma unroll
        for (int off = 1; off < 64; off <<= 1) {
            r0 += __shfl_xor(r0, off, 64);
            r1 += __shfl_xor(r1, off, 64);
        }
        if (lane == 0) { red0[wave] = r0; red1[wave] = r1; }
        __syncthreads();
        if (c == 0)
            gb[blk] = make_float2(red0[0] + red0[1] + red0[2] + red0[3],
                                  red1[0] + red1[1] + red1[2] + red1[3]);
    } else {
        int i2 = (blk - 384) * 256 + c;
        wo[i2] = f2bf(Wo[i2]);
    }
}

// ---------------------------------------------------------------------------
// Kernel 1: LayerNorm-folded QKV projection (unchanged r15).
// ---------------------------------------------------------------------------
__global__ __launch_bounds__(512) void k_ln_qkv(
    const float* __restrict__ x, const short* __restrict__ wqkv, const float2* __restrict__ gb,
    short* __restrict__ q, short* __restrict__ k, short* __restrict__ v)
{
    __shared__ short xnT[32 * 264];
    __shared__ short st2[128 * 48];
    __shared__ float ps_[8 * 32], ps2_[8 * 32];
    const int b   = blockIdx.y;
    const int l0  = blockIdx.x * 32;
    const int tid = threadIdx.x;
    const int wave = tid >> 6, lane = tid & 63;

    {
        const int ls = tid & 31;
        const int cg = tid >> 5;
        float s = 0.f, s2 = 0.f;
        #pragma unroll
        for (int kk = 0; kk < 8; ++kk) {
            int c = 2 * cg + 32 * kk;
            float t0 = x[((size_t)b * CC_ + c) * LL_ + l0 + ls];
            float t1 = x[((size_t)b * CC_ + c + 1) * LL_ + l0 + ls];
            s += t0 + t1; s2 += t0 * t0 + t1 * t1;
            unsigned pk = (unsigned short)f2bf(t0) | ((unsigned)(unsigned short)f2bf(t1) << 16);
            *(unsigned*)(xnT + ls * 264 + c) = pk;
        }
        s  += __shfl_xor(s, 32, 64);
        s2 += __shfl_xor(s2, 32, 64);
        if (lane < 32) { ps_[wave * 32 + lane] = s; ps2_[wave * 32 + lane] = s2; }
    }
    __syncthreads();

    const int n = lane & 15, quad = lane >> 4;
    const int rowbase = (wave >> 2) * 16;
    const int colbase = (wave & 3) * 96;

    v4f acc[6];
    #pragma unroll
    for (int ct = 0; ct < 6; ++ct) acc[ct] = (v4f){0.f, 0.f, 0.f, 0.f};

    #pragma unroll
    for (int ks = 0; ks < 8; ++ks) {
        const v8s af = *(const v8s*)(xnT + (rowbase + n) * 264 + ks * 32 + quad * 8);
        #pragma unroll
        for (int ct = 0; ct < 6; ++ct) {
            const v8s bfrag = *(const v8s*)(wqkv + (size_t)(colbase + ct * 16 + n) * 256 + ks * 32 + quad * 8);
            acc[ct] = __builtin_amdgcn_mfma_f32_16x16x32_bf16(af, bfrag, acc[ct], 0, 0, 0);
        }
    }
    __syncthreads();

    float rsv[4], rmv[4];
    #pragma unroll
    for (int r = 0; r < 4; ++r) {
        int l = rowbase + quad * 4 + r;
        float s = 0.f, s2 = 0.f;
        #pragma unroll
        for (int p = 0; p < 8; ++p) { s += ps_[p * 32 + l]; s2 += ps2_[p * 32 + l]; }
        float mean = s * (1.f / CC_);
        float var  = s2 * (1.f / CC_) - mean * mean;
        float rs   = rsqrtf(var + EPS_);
        rsv[r] = rs; rmv[r] = rs * mean;
    }
    #pragma unroll
    for (int ct = 0; ct < 6; ++ct) {
        int o = colbase + ct * 16 + n;
        float2 gbo = gb[o];
        #pragma unroll
        for (int r = 0; r < 4; ++r) {
            int l = rowbase + quad * 4 + r;
            float val = rsv[r] * acc[ct][r] - rmv[r] * gbo.x + gbo.y;
            if (o < 256)      xnT[l * 264 + o] = f2bf(val);
            else              st2[(o - 256) * 48 + l] = f2bf(val);
        }
    }
    __syncthreads();

    {
        int u = tid;
        int h = u >> 7, rest = u & 127;
        int l = rest >> 2, dg = rest & 3;
        size_t bh = (size_t)b * HEADS_ + h;
        v8s qv = *(const v8s*)(xnT + l * 264 + h * 32 + dg * 8);
        *(v8s*)(q + (bh * LL_ + l0 + l) * DHEAD_ + dg * 8) = qv;
        v8s kv = *(const v8s*)(xnT + l * 264 + 128 + h * 32 + dg * 8);
        *(v8s*)(k + (bh * LL_ + l0 + l) * DHEAD_ + dg * 8) = kv;

        int op = u >> 2, lg = u & 3;
        v8s vv = *(const v8s*)(st2 + op * 48 + lg * 8);
        int h2 = op >> 5, d = op & 31;
        *(v8s*)(v + (((size_t)b * HEADS_ + h2) * DHEAD_ + d) * LL_ + l0 + lg * 8) = vv;
    }
}

// ---------------------------------------------------------------------------
// Kernel 2: flash attention (r15 structure) + REGISTER DOUBLE-BUFFERED
// staging: chunk i+1's K/V global loads issue during chunk i's compute;
// between barriers only fast LDS writes remain (no exposed HBM latency).
// ---------------------------------------------------------------------------
__global__ __launch_bounds__(512) void k_attn(
    const short* __restrict__ q, const short* __restrict__ k, const short* __restrict__ v,
    short* __restrict__ ao)
{
    __shared__ char smem[20480 + 17408 + 512];
    short* Kb     = (short*)smem;                      // [2][128*40]  (hh*5120)
    short* Vb     = (short*)(smem + 20480);            // [2][32*136]  (hh*4352)
    float* Ost    = (float*)smem;                      // alias Kb: [4][32][32]
    float* psumst = (float*)(smem + 20480 + 17408);    // [4*32]

    const int bh   = blockIdx.y;
    const int b    = bh >> 2, h = bh & 3;
    const int tid  = threadIdx.x;
    const int wave = tid >> 6, lane = tid & 63;
    const int wq   = wave & 3;           // q-subtile
    const int kh   = wave >> 2;          // key half: [kh*1024, +1024)
    const int m    = lane & 31;
    const int half = lane >> 5;
    const size_t kvbase = (size_t)bh * LL_ * DHEAD_;   // q,k: [bh][l][32]
    const size_t vbase  = (size_t)bh * DHEAD_ * LL_;   // v:   [bh][d][L]

    const int q0 = blockIdx.x * 128 + wq * 32;

    const v8s qf0 = *(const v8s*)(q + kvbase + (size_t)(q0 + m) * DHEAD_ + half * 8);
    const v8s qf1 = *(const v8s*)(q + kvbase + (size_t)(q0 + m) * DHEAD_ + 16 + half * 8);

    v16f O = {};
    float psum = 0.f;

    // staging coords (whole block stages both halves each chunk)
    const int s_hh  = (tid >> 7) & 1;     // which key-half for K staging
    const int s_r   = tid & 127;          // key row
    const int s_p   = tid >> 8;           // 16-half part (0/1)
    const int v_hh  = tid >> 8;           // which key-half for V staging
    const int v_d   = (tid >> 3) & 31;    // d row
    const int v_cg  = tid & 7;            // 16-half col group

    const short* ksrc0 = k + kvbase + (size_t)(s_hh * 1024 + s_r) * DHEAD_ + s_p * 16;
    const short* vsrc0 = v + vbase + (size_t)v_d * LL_ + v_hh * 1024 + v_cg * 16;
    short* kdst = Kb + s_hh * 5120 + s_r * 40 + s_p * 16;
    short* vdst = Vb + v_hh * 4352 + v_d * 136 + v_cg * 16;

    // prologue: chunk 0 into registers
    v8s kr0 = *(const v8s*)(ksrc0);
    v8s kr1 = *(const v8s*)(ksrc0 + 8);
    v8s vr0 = *(const v8s*)(vsrc0);
    v8s vr1 = *(const v8s*)(vsrc0 + 8);

    for (int kc = 0; kc < 1024; kc += 128) {
        __syncthreads();   // previous chunk's readers done
        *(v8s*)kdst       = kr0;
        *(v8s*)(kdst + 8) = kr1;
        *(v8s*)vdst       = vr0;
        *(v8s*)(vdst + 8) = vr1;
        if (kc < 896) {    // prefetch next chunk; completes during compute
            const short* kn = ksrc0 + (size_t)(kc + 128) * DHEAD_;
            const short* vn = vsrc0 + (kc + 128);
            kr0 = *(const v8s*)(kn);
            kr1 = *(const v8s*)(kn + 8);
            vr0 = *(const v8s*)(vn);
            vr1 = *(const v8s*)(vn + 8);
        }
        __syncthreads();   // staging visible

        const short* Kw = Kb + kh * 5120;
        const short* Vw = Vb + kh * 4352;
        #pragma unroll
        for (int ktl = 0; ktl < 128; ktl += 32) {
            const v8s kf0 = *(const v8s*)(Kw + (ktl + m) * 40 + half * 8);
            const v8s kf1 = *(const v8s*)(Kw + (ktl + m) * 40 + 16 + half * 8);
            v16f S = __builtin_amdgcn_mfma_f32_32x32x16_bf16(kf0, qf0, (v16f){}, 0, 0, 0);
            S      = __builtin_amdgcn_mfma_f32_32x32x16_bf16(kf1, qf1, S,        0, 0, 0);

            const v8s vf0 = *(const v8s*)(Vw + m * 136 + ktl + half * 8);
            const v8s vf1 = *(const v8s*)(Vw + m * 136 + ktl + 16 + half * 8);

            unsigned e[8];
            #pragma unroll
            for (int i = 0; i < 8; ++i) {
                float pa = __builtin_amdgcn_exp2f(S[2 * i]);
                float pb = __builtin_amdgcn_exp2f(S[2 * i + 1]);
                psum += pa + pb;
                e[i] = __builtin_amdgcn_perm(fbits(pb) + 0x8000u, fbits(pa) + 0x8000u, 0x07060302u);
            }
            v4u f1, f2;
#if __has_builtin(__builtin_amdgcn_permlane32_swap)
            {
                auto r02 = __builtin_amdgcn_permlane32_swap(e[0], e[2], false, false);
                auto r13 = __builtin_amdgcn_permlane32_swap(e[1], e[3], false, false);
                auto r46 = __builtin_amdgcn_permlane32_swap(e[4], e[6], false, false);
                auto r57 = __builtin_amdgcn_permlane32_swap(e[5], e[7], false, false);
                f1 = (v4u){r02[0], r13[0], r02[1], r13[1]};
                f2 = (v4u){r46[0], r57[0], r46[1], r57[1]};
            }
#else
            {
                unsigned o0 = __shfl_xor(e[0], 32, 64), o1 = __shfl_xor(e[1], 32, 64);
                unsigned o2 = __shfl_xor(e[2], 32, 64), o3 = __shfl_xor(e[3], 32, 64);
                unsigned o4 = __shfl_xor(e[4], 32, 64), o5 = __shfl_xor(e[5], 32, 64);
                unsigned o6 = __shfl_xor(e[6], 32, 64), o7 = __shfl_xor(e[7], 32, 64);
                f1 = half ? (v4u){o2, o3, e[2], e[3]} : (v4u){e[0], e[1], o0, o1};
                f2 = half ? (v4u){o6, o7, e[6], e[7]} : (v4u){e[4], e[5], o4, o5};
            }
#endif
            O = __builtin_amdgcn_mfma_f32_32x32x16_bf16(__builtin_bit_cast(v8s, f1), vf0, O, 0, 0, 0);
            O = __builtin_amdgcn_mfma_f32_32x32x16_bf16(__builtin_bit_cast(v8s, f2), vf1, O, 0, 0, 0);
        }
    }

    psum += __shfl_xor(psum, 32, 64);    // lane m: den-partial for q = m

    __syncthreads();   // all waves done reading Kb before Ost (alias) writes
    if (kh == 1) {
        #pragma unroll
        for (int r = 0; r < 16; ++r) {
            int qr = (r & 3) + 8 * (r >> 2) + 4 * half;
            Ost[(wq * 32 + qr) * 32 + m] = O[r];
        }
        if (half == 0) psumst[wq * 32 + m] = psum;
    }
    __syncthreads();
    if (kh == 0) {
        float den = psum + psumst[wq * 32 + m];
        float invden = 1.f / den;
        #pragma unroll
        for (int r = 0; r < 16; ++r) {
            int qr = (r & 3) + 8 * (r >> 2) + 4 * half;
            float inv = __shfl(invden, qr, 64);
            float val = (O[r] + Ost[(wq * 32 + qr) * 32 + m]) * inv;
            int row = q0 + qr;
            ao[((size_t)b * LL_ + row) * HID_ + h * DHEAD_ + m] = f2bf(val);
        }
    }
}

// ---------------------------------------------------------------------------
// Kernel 3: output projection (r15) + EARLY x prefetch: the residual loads
// issue at kernel entry and complete under the fragment loads + MFMAs.
// ---------------------------------------------------------------------------
__global__ __launch_bounds__(256) void k_oproj(
    const short* __restrict__ ao, const short* __restrict__ wo, const float* __restrict__ bo,
    const float* __restrict__ x, float* __restrict__ out)
{
    const int b = blockIdx.z;
    const int l0 = blockIdx.x * 32;
    const int tid = threadIdx.x;
    const int wave = tid >> 6, lane = tid & 63;
    const int m = lane & 31, half = lane >> 5;
    const int o0 = blockIdx.y * 128 + wave * 32;

    // early residual prefetch (independent of everything below)
    float xv[16]; float bv_[16];
    #pragma unroll
    for (int r = 0; r < 16; ++r) {
        int o = o0 + (r & 3) + 8 * (r >> 2) + 4 * half;
        xv[r]  = x[((size_t)b * CC_ + o) * LL_ + l0 + m];
        bv_[r] = bo[o];
    }

    v8s bf[8];
    #pragma unroll
    for (int ks = 0; ks < 8; ++ks)
        bf[ks] = *(const v8s*)(ao + ((size_t)b * LL_ + l0 + m) * HID_ + ks * 16 + half * 8);

    v16f acc = {};
    #pragma unroll
    for (int ks = 0; ks < 8; ++ks) {
        const v8s af = *(const v8s*)(wo + (size_t)(o0 + m) * HID_ + ks * 16 + half * 8);
        acc = __builtin_amdgcn_mfma_f32_32x32x16_bf16(af, bf[ks], acc, 0, 0, 0);
    }

    #pragma unroll
    for (int r = 0; r < 16; ++r) {
        int o = o0 + (r & 3) + 8 * (r >> 2) + 4 * half;
        size_t oi = ((size_t)b * CC_ + o) * LL_ + l0 + m;
        out[oi] = acc[r] + bv_[r] + xv[r];
    }
}

extern "C" void kernel_launch(void* const* d_in, const int* in_sizes, int n_in,
                              void* d_out, int out_size, void* d_ws, size_t ws_size,
                              hipStream_t stream) {
    const float* x  = (const float*)d_in[0];
    const float* g  = (const float*)d_in[1];
    const float* bv = (const float*)d_in[2];
    const float* Wq = (const float*)d_in[3];
    const float* Wk = (const float*)d_in[4];
    const float* Wv = (const float*)d_in[5];
    const float* Wo = (const float*)d_in[6];
    const float* bo = (const float*)d_in[7];
    float* out = (float*)d_out;

    const size_t qkv_elems = (size_t)BB_ * HEADS_ * LL_ * DHEAD_;
    short* q    = (short*)d_ws;
    short* k    = q + qkv_elems;
    short* v    = k + qkv_elems;
    short* ao   = v + qkv_elems;
    short* wqkv = ao + qkv_elems;
    short* wo   = wqkv + 384 * 256;
    float2* gb  = (float2*)(wo + 256 * 128);

    k_prep  <<<dim3(512), dim3(256), 0, stream>>>(Wq, Wk, Wv, Wo, g, bv, wqkv, wo, gb);
    k_ln_qkv<<<dim3(LL_ / 32, BB_), dim3(512), 0, stream>>>(x, wqkv, gb, q, k, v);
    k_attn  <<<dim3(LL_ / 128, BB_ * HEADS_), dim3(512), 0, stream>>>(q, k, v, ao);
    k_oproj <<<dim3(LL_ / 32, 2, BB_), dim3(256), 0, stream>>>(ao, wo, bo, x, out);
}